// Round 12
// baseline (392.181 us; speedup 1.0000x reference)
//
#include <hip/hip_runtime.h>
#include <hip/hip_bf16.h>

#define B_    8
#define NP    2352
#define D_    512
#define SENT  48
#define PAIRS 512
#define NERL  16
#define REL   32
#define MTOT  (B_*NP)   // 18816
#define SLOTB 640       // slots per batch (48 ner + up to 148 pairs * 4)
#define MG    (B_*SLOTB) // 5120 gathered slots = 80 tiles of 64

typedef unsigned short u16;
typedef __bf16 bf16x8 __attribute__((ext_vector_type(8)));
typedef float  f32x4  __attribute__((ext_vector_type(4)));

__device__ __forceinline__ u16 f2b(float f) {
  union { float f; unsigned u; } c; c.f = f;
  unsigned u = c.u;
  u += 0x7fffu + ((u >> 16) & 1u);           // round-to-nearest-even
  return (u16)(u >> 16);
}
__device__ __forceinline__ float b2f(u16 h) {
  union { unsigned u; float f; } c; c.u = ((unsigned)h) << 16;
  return c.f;
}
__device__ __forceinline__ void gload16(const u16* g, u16* lds) {
  __builtin_amdgcn_global_load_lds(
      (const __attribute__((address_space(1))) unsigned*)g,
      (__attribute__((address_space(3))) unsigned*)lds, 16, 0, 0);
}

// ----------------------------------------------------------------- zero ----
__global__ void zero_zp(u16* zp) { zp[threadIdx.x] = 0; }

// ------------------------------------------------------------- prep_adj ----
__global__ __launch_bounds__(256) void prep_adj(const float* __restrict__ adj,
                                                u16* __restrict__ adjb,
                                                float* __restrict__ rdenom) {
  const int row = blockIdx.x;                 // 0..18815
  const float4* src = (const float4*)(adj + (size_t)row * NP);
  ushort4* dst = (ushort4*)(adjb + (size_t)row * NP);
  float s = 0.f;
  for (int i = threadIdx.x; i < NP / 4; i += 256) {
    float4 v = src[i];
    s += (v.x + v.y) + (v.z + v.w);
    ushort4 o; o.x = f2b(v.x); o.y = f2b(v.y); o.z = f2b(v.z); o.w = f2b(v.w);
    dst[i] = o;
  }
  #pragma unroll
  for (int o = 32; o > 0; o >>= 1) s += __shfl_down(s, o, 64);
  __shared__ float red[4];
  int w = threadIdx.x >> 6, l = threadIdx.x & 63;
  if (l == 0) red[w] = s;
  __syncthreads();
  if (threadIdx.x == 0)
    rdenom[row] = 1.f / (red[0] + red[1] + red[2] + red[3] + 1.f);
}

// ------------------------------------------------------------- pair_prep ---
__global__ __launch_bounds__(512) void pair_prep(const int* __restrict__ ps,
                                                 const int* __restrict__ hs,
                                                 const int* __restrict__ ts,
                                                 const float* __restrict__ rdenom,
                                                 int* __restrict__ rowmap,
                                                 int* __restrict__ pslot,
                                                 float* __restrict__ rdenom_g) {
  __shared__ int sps[PAIRS];
  const int t = threadIdx.x;
  sps[t] = ps[t];
  for (int i = t; i < MG; i += 512) rowmap[i] = 0;
  __syncthreads();
  if (t < B_ * SENT) {                       // ner slots
    int b = t / SENT, j = t % SENT;
    rowmap[b * SLOTB + j] = j;
  }
  const int b = sps[t];
  int rank = 0;
  for (int q = 0; q < t; ++q) rank += (sps[q] == b) ? 1 : 0;
  const int h = hs[t], tt = ts[t];
  const int s0 = b * SLOTB + SENT + 4 * rank;
  rowmap[s0 + 0] = (h + 1) * SENT + tt;
  rowmap[s0 + 1] = (h + 1) * SENT + tt + 1;
  rowmap[s0 + 2] = (h + 2) * SENT + tt;
  rowmap[s0 + 3] = (h + 2) * SENT + tt + 1;
  pslot[t] = s0;
  __syncthreads();
  for (int i = t; i < MG; i += 512)
    rdenom_g[i] = rdenom[(i / SLOTB) * NP + rowmap[i]];
}

// ----------------------------------------------------- transpose-convert ---
__global__ __launch_bounds__(256) void tcvt(const float* __restrict__ in_,
                                            u16* __restrict__ out,
                                            int R, int C, size_t inb, size_t outb) {
  __shared__ u16 tile[64][65];
  const int b  = blockIdx.z;
  const int r0 = blockIdx.x * 64, c0 = blockIdx.y * 64;
  const int t  = threadIdx.x;
  const int tr = t >> 4, tc = (t & 15) * 4;
  #pragma unroll
  for (int i = 0; i < 4; ++i) {
    int rl = i * 16 + tr;
    int r  = r0 + rl;
    if (r < R) {
      const float* in = in_ + (size_t)b * inb + (size_t)r * C + c0 + tc;
      float4 v = *(const float4*)in;
      tile[rl][tc + 0] = f2b(v.x); tile[rl][tc + 1] = f2b(v.y);
      tile[rl][tc + 2] = f2b(v.z); tile[rl][tc + 3] = f2b(v.w);
    }
  }
  __syncthreads();
  const int c  = t >> 2;
  const int rb = (t & 3) * 16;
  u16* orow = out + (size_t)b * outb + (size_t)(c0 + c) * R + r0;
  #pragma unroll
  for (int i = 0; i < 4; ++i) {
    int rl = rb + i * 4;
    int r  = r0 + rl;
    if (r + 3 < R) {
      ushort4 v;
      v.x = tile[rl + 0][c]; v.y = tile[rl + 1][c];
      v.z = tile[rl + 2][c]; v.w = tile[rl + 3][c];
      *(ushort4*)(orow + rl) = v;
    } else {
      for (int j = 0; j < 4; ++j)
        if (r + j < R) orow[rl + j] = tile[rl + j][c];
    }
  }
}

// ---------------------------- 2-wave 64x128 GEMM (m97 recipe, small tile) --
// BM=64, BN=128, BK=32, 128 thr (2 waves, each 64x64 = 4x4 16x16x32 frags).
// Single-buffered 12 KB LDS + plain __syncthreads -> grid 1184/1176 gives
// ~4.6 UNCOUPLED blocks/CU; cross-block wave overlap hides the per-block
// stage/drain stalls (m97/m114 mechanism; R8/R9 showed coupled schemes fail).
// Slot swizzle slot = lq ^ ((row>>1)&3) on BOTH sides -> 0 bank conflicts.
// K-tail / lookahead -> zero page. GATHER=1: M = 5120 slots via rowmap.
template<int MODE, int WRITE_T, int GATHER>
__global__ __launch_bounds__(128) void gemm8(
    const u16* __restrict__ A, const u16* __restrict__ A2,
    const u16* __restrict__ Bm, const u16* __restrict__ Xt,
    const float* __restrict__ bias, const float* __restrict__ rdenom,
    const int* __restrict__ rowmap,
    const u16* __restrict__ zp, u16* __restrict__ out, u16* __restrict__ outT)
{
  constexpr int KACT   = (MODE == 0) ? NP : (MODE == 1 ? 512 : 1024);
  constexpr int KTILES = (KACT + 31) / 32;     // 74 / 16 / 32
  constexpr int LDA    = (MODE == 0) ? NP : 512;
  constexpr int LDB    = KACT;

  int m0, n0, bat = 0;
  const u16* Ab = A;
  const u16* Bb = Bm;
  const u16* Xb = Xt;
  size_t outBase = 0;
  if constexpr (GATHER) {
    // grid 320 = 8 XCDs x 40; 80 m-tiles (10/batch) x 4 n-tiles
    const int bx  = blockIdx.x;
    const int rid = (bx & 7) * 40 + (bx >> 3);
    const int mt  = rid >> 2;                 // 0..79
    n0 = (rid & 3) << 7;
    m0 = mt * 64;                             // slot-space (640 = 10*64)
    bat = mt / 10;
    if constexpr (MODE == 0) {
      Ab = A  + (size_t)bat * NP * NP;
      Bb = Bm + (size_t)bat * 512 * NP;
    }
  } else if constexpr (MODE == 0) {
    // grid 1184 = 8 XCD chunks x 148 (one batch per chunk); 37 m x 4 n
    const int bx  = blockIdx.x;
    bat = bx & 7;
    const int loc = bx >> 3;                  // 0..147
    const int mt  = loc >> 2;                 // 0..36
    n0 = (loc & 3) << 7;
    m0 = (mt < 36) ? mt * 64 : NP - 64;       // overlap last tile
    Ab = A  + (size_t)bat * NP * NP;
    Bb = Bm + (size_t)bat * 512 * NP;
    Xb = Xt + (size_t)bat * 512 * NP;
    outBase = (size_t)bat * NP * 512;
  } else {
    // grid 1176 = 8 XCDs x 147 exactly; 294 m-tiles x 4 n
    const int bx  = blockIdx.x;
    const int rid = (bx & 7) * 147 + (bx >> 3);
    const int mt  = rid >> 2;                 // 0..293
    n0 = (rid & 3) << 7;
    m0 = mt * 64;                             // exact (294*64 = 18816)
  }

  // single buffer: As [64 rows][4 slots x 8 u16] = 4 KB, Bs [128][..] = 8 KB
  __shared__ __align__(16) u16 As[2048];
  __shared__ __align__(16) u16 Bs[4096];

  const int tid = threadIdx.x;               // 0..127
  const int l  = tid & 63;
  const int w  = tid >> 6;                   // wave 0..1 (n-split)
  const int lr = l & 15, lq = l >> 4;

  f32x4 acc[4][4];
  #pragma unroll
  for (int i = 0; i < 4; ++i)
    #pragma unroll
    for (int j = 0; j < 4; ++j)
      acc[i][j] = (f32x4){0.f, 0.f, 0.f, 0.f};

  // A-row gather (MODE 0 adj rows, MODE 2 g0 half); MODE 1 A is slot-major.
  int rsrcA[2];
  #pragma unroll
  for (int j = 0; j < 2; ++j) {
    const int row = (j * 128 + tid) >> 2;    // 0..63
    if constexpr (GATHER && MODE != 1) rsrcA[j] = rowmap[m0 + row];
    else                               rsrcA[j] = m0 + row;
  }

  auto STAGE = [&](int kt) {
    #pragma unroll
    for (int j = 0; j < 2; ++j) {            // A: 256 chunks
      const int cl   = j * 128 + tid;
      const int row  = cl >> 2, slot = cl & 3;
      const int gch  = kt * 4 + (slot ^ ((row >> 1) & 3));
      const u16* src;
      if constexpr (MODE == 2) {
        if constexpr (GATHER) {
          src = (gch < 64)
              ? A  + ((size_t)bat * NP + rsrcA[j]) * 512 + gch * 8
              : A2 + (size_t)(m0 + row) * 512 + (gch - 64) * 8;
        } else {
          src = (gch < 64) ? A  + (size_t)(m0 + row) * 512 + gch * 8
                           : A2 + (size_t)(m0 + row) * 512 + (gch - 64) * 8;
        }
      } else {
        src = Ab + (size_t)rsrcA[j] * LDA + gch * 8;
      }
      if (gch * 8 + 8 > KACT) src = zp;
      gload16(src, As + cl * 8);
    }
    #pragma unroll
    for (int j = 0; j < 4; ++j) {            // B: 512 chunks
      const int cl   = j * 128 + tid;
      const int row  = cl >> 2, slot = cl & 3;
      const int gch  = kt * 4 + (slot ^ ((row >> 1) & 3));
      const u16* src = Bb + (size_t)(n0 + row) * LDB + gch * 8;
      if (gch * 8 + 8 > KACT) src = zp;
      gload16(src, Bs + cl * 8);
    }
  };

  for (int kt = 0; kt < KTILES; ++kt) {
    STAGE(kt);
    __syncthreads();                          // drain loads; tile visible
    bf16x8 af[4], bg[4];
    #pragma unroll
    for (int f = 0; f < 4; ++f) {
      const int ra = f * 16 + lr;             // 0..63
      af[f] = *(const bf16x8*)(As + ra * 32 + ((lq ^ ((ra >> 1) & 3)) << 3));
      const int rb = w * 64 + f * 16 + lr;    // 0..127
      bg[f] = *(const bf16x8*)(Bs + rb * 32 + ((lq ^ ((rb >> 1) & 3)) << 3));
    }
    #pragma unroll
    for (int mf = 0; mf < 4; ++mf)
      #pragma unroll
      for (int nf = 0; nf < 4; ++nf)
        acc[mf][nf] = __builtin_amdgcn_mfma_f32_16x16x32_bf16(
            af[mf], bg[nf], acc[mf][nf], 0, 0, 0);
    __syncthreads();                          // reads done before overwrite
  }

  // --------------------------------------------------------- epilogue ----
  #pragma unroll
  for (int mf = 0; mf < 4; ++mf) {
    const int gm0 = m0 + mf * 16 + lq * 4;
    f32x4 rd;
    if constexpr (MODE == 1) rd = *(const f32x4*)(rdenom + gm0);
    int rsm[4];
    if constexpr (GATHER && MODE == 0) {
      #pragma unroll
      for (int r = 0; r < 4; ++r) rsm[r] = rowmap[gm0 + r];
    }
    #pragma unroll
    for (int nf = 0; nf < 4; ++nf) {
      const int gn = n0 + w * 64 + nf * 16 + lr;
      u16 ov[4];
      if constexpr (MODE == 0) {
        float xf[4];
        if constexpr (GATHER) {
          #pragma unroll
          for (int r = 0; r < 4; ++r)
            xf[r] = b2f(Xt[((size_t)bat * NP + rsm[r]) * 512 + gn]);
        } else {
          ushort4 xv = *(const ushort4*)(Xb + (size_t)gn * NP + gm0);
          xf[0] = b2f(xv.x); xf[1] = b2f(xv.y);
          xf[2] = b2f(xv.z); xf[3] = b2f(xv.w);
        }
        #pragma unroll
        for (int r = 0; r < 4; ++r) ov[r] = f2b(acc[mf][nf][r] + xf[r]);
      } else if constexpr (MODE == 1) {
        const float bn = 2.f * bias[gn];
        #pragma unroll
        for (int r = 0; r < 4; ++r)
          ov[r] = f2b(fmaxf((acc[mf][nf][r] + bn) * rd[r], 0.f));
      } else {
        const float bn = bias[gn];
        #pragma unroll
        for (int r = 0; r < 4; ++r) ov[r] = f2b(acc[mf][nf][r] + bn);
      }
      #pragma unroll
      for (int r = 0; r < 4; ++r)
        out[outBase + (size_t)(gm0 + r) * 512 + gn] = ov[r];
      if constexpr (WRITE_T) {
        const int bb = gm0 / NP;               // quad never straddles batch
        const int ml = gm0 - bb * NP;
        ushort4 tv; tv.x = ov[0]; tv.y = ov[1]; tv.z = ov[2]; tv.w = ov[3];
        *(ushort4*)(outT + ((size_t)bb * 512 + gn) * NP + ml) = tv;
      }
    }
  }
}

// ------------------------------------------------------------- ner head ----
__global__ __launch_bounds__(64) void ner_kernel(const float* __restrict__ ner,
                                                 const u16* __restrict__ logits_g,
                                                 const float* __restrict__ nw,
                                                 const float* __restrict__ nb,
                                                 float* __restrict__ out) {
  int r = blockIdx.x;                 // 0..383
  int b = r / SENT, tp = r % SENT;
  int lane = threadIdx.x;
  const float* nrow = ner      + ((size_t)b * SENT  + tp) * D_;
  const u16*   lrow = logits_g + ((size_t)b * SLOTB + tp) * D_;
  float rv[16];
  #pragma unroll
  for (int i = 0; i < 8; ++i) rv[i]     = nrow[lane + i * 64];
  #pragma unroll
  for (int i = 0; i < 8; ++i) rv[8 + i] = b2f(lrow[lane + i * 64]);
  for (int j = 0; j < NERL; ++j) {
    float s = 0.f;
    #pragma unroll
    for (int i = 0; i < 16; ++i)
      s = fmaf(rv[i], nw[(size_t)(lane + i * 64) * NERL + j], s);
    for (int o = 32; o > 0; o >>= 1) s += __shfl_down(s, o);
    if (lane == 0) out[r * NERL + j] = s + nb[j];
  }
}

// ----------------------------------------------------------- pair + re -----
__global__ __launch_bounds__(256) void pair_kernel(const u16* __restrict__ logits_g,
                                                   const float* __restrict__ refeat,
                                                   const float* __restrict__ rw,
                                                   const float* __restrict__ rb,
                                                   const int* __restrict__ pslot,
                                                   float* __restrict__ out) {
  int p = blockIdx.x;
  __shared__ float avg[D_];
  const u16* r0 = logits_g + (size_t)pslot[p] * D_;   // 4 consecutive slots
  for (int dd = threadIdx.x; dd < D_; dd += 256)
    avg[dd] = 0.25f * (b2f(r0[dd]) + b2f(r0[D_ + dd]) +
                       b2f(r0[2 * D_ + dd]) + b2f(r0[3 * D_ + dd]));
  __syncthreads();
  int wave = threadIdx.x >> 6, lane = threadIdx.x & 63;
  const float* rf = refeat + (size_t)p * D_;
  for (int jj = 0; jj < 8; ++jj) {
    int j = wave * 8 + jj;
    float s = 0.f;
    #pragma unroll
    for (int i = 0; i < 8; ++i) {
      int k = lane + i * 64;
      s = fmaf(rf[k],  rw[(size_t)k * REL + j], s);
      s = fmaf(avg[k], rw[(size_t)(k + D_) * REL + j], s);
    }
    for (int o = 32; o > 0; o >>= 1) s += __shfl_down(s, o);
    if (lane == 0) out[p * REL + j] = s + rb[j];
  }
}

// --------------------------------------------------------------- launch ----
extern "C" void kernel_launch(void* const* d_in, const int* in_sizes, int n_in,
                              void* d_out, int out_size, void* d_ws, size_t ws_size,
                              hipStream_t stream) {
  const float* inputs = (const float*)d_in[0];
  const float* ner    = (const float*)d_in[1];
  const float* refeat = (const float*)d_in[2];
  const float* adj    = (const float*)d_in[3];
  const float* W0w    = (const float*)d_in[4];
  const float* W0b    = (const float*)d_in[5];
  const float* W1w    = (const float*)d_in[6];
  const float* W1b    = (const float*)d_in[7];
  const float* outw   = (const float*)d_in[8];
  const float* outb   = (const float*)d_in[9];
  const float* nerw   = (const float*)d_in[10];
  const float* nerb   = (const float*)d_in[11];
  const float* rew    = (const float*)d_in[12];
  const float* reb    = (const float*)d_in[13];
  const int*   ps     = (const int*)d_in[14];
  const int*   hs     = (const int*)d_in[15];
  const int*   ts     = (const int*)d_in[16];
  (void)in_sizes; (void)n_in; (void)out_size; (void)ws_size;
  float* outp = (float*)d_out;

  char* ws = (char*)d_ws;
  size_t off = 0;
  u16* adj_bf = (u16*)(ws + off); off += (size_t)B_ * NP * NP * 2;  // 88.5 MB
  float* rdenom = (float*)(ws + off); off += (size_t)MTOT * 4;
  u16* zp  = (u16*)(ws + off); off += 512;
  u16* w0t = (u16*)(ws + off); off += 512 * 512 * 2;
  u16* w1t = (u16*)(ws + off); off += 512 * 512 * 2;
  u16* owt = (u16*)(ws + off); off += 512 * 1024 * 2;
  u16* xt  = (u16*)(ws + off); off += (size_t)B_ * 512 * NP * 2;   // x0t / g0t
  u16* S   = (u16*)(ws + off); off += (size_t)MTOT * 512 * 2;
  u16* g0  = (u16*)(ws + off); off += (size_t)MTOT * 512 * 2;
  int* rowmap = (int*)(ws + off); off += (size_t)MG * 4;
  int* pslot  = (int*)(ws + off); off += (size_t)PAIRS * 4;
  float* rdenom_g = (float*)(ws + off); off += (size_t)MG * 4;
  u16* S_g      = (u16*)(ws + off); off += (size_t)MG * 512 * 2;
  u16* g1_g     = (u16*)(ws + off); off += (size_t)MG * 512 * 2;
  u16* logits_g = (u16*)(ws + off); off += (size_t)MG * 512 * 2;

  zero_zp<<<1, 256, 0, stream>>>(zp);
  prep_adj<<<MTOT, 256, 0, stream>>>(adj, adj_bf, rdenom);
  pair_prep<<<1, 512, 0, stream>>>(ps, hs, ts, rdenom, rowmap, pslot, rdenom_g);

  dim3 gT((NP + 63) / 64, D_ / 64, B_);         // (37, 8, 8)
  tcvt<<<gT, 256, 0, stream>>>(inputs, xt, NP, D_, (size_t)NP * D_, (size_t)D_ * NP);
  tcvt<<<dim3(8, 8, 1),  256, 0, stream>>>(W0w,  w0t, 512,  512, 0, 0);
  tcvt<<<dim3(8, 8, 1),  256, 0, stream>>>(W1w,  w1t, 512,  512, 0, 0);
  tcvt<<<dim3(16, 8, 1), 256, 0, stream>>>(outw, owt, 1024, 512, 0, 0);

  // Layer 1 (full): S = adj@x + x ; g0 = relu((S@W0 + 2b)/denom) (+g0^T)
  gemm8<0,0,0><<<1184, 128, 0, stream>>>(adj_bf, nullptr, xt, xt,
                                         nullptr, nullptr, nullptr, zp, S, nullptr);
  gemm8<1,1,0><<<1176, 128, 0, stream>>>(S, nullptr, w0t, nullptr,
                                         W0b, rdenom, nullptr, zp, g0, xt);
  // Layer 2 (gathered, M = 5120 slots)
  gemm8<0,0,1><<<320, 128, 0, stream>>>(adj_bf, nullptr, xt, g0,
                                        nullptr, nullptr, rowmap, zp, S_g, nullptr);
  gemm8<1,0,1><<<320, 128, 0, stream>>>(S_g, nullptr, w1t, nullptr,
                                        W1b, rdenom_g, rowmap, zp, g1_g, nullptr);
  gemm8<2,0,1><<<320, 128, 0, stream>>>(g0, g1_g, owt, nullptr,
                                        outb, nullptr, rowmap, zp, logits_g, nullptr);

  ner_kernel <<<B_ * SENT, 64,  0, stream>>>(ner, logits_g, nerw, nerb, outp);
  pair_kernel<<<PAIRS,     256, 0, stream>>>(logits_g, refeat, rew, reb, pslot,
                                             outp + B_ * SENT * NERL);
}

// Round 13
// 360.133 us; speedup vs baseline: 1.0890x; 1.0890x over previous
//
#include <hip/hip_runtime.h>
#include <hip/hip_bf16.h>

#define B_    8
#define NP    2352
#define D_    512
#define SENT  48
#define PAIRS 512
#define NERL  16
#define REL   32
#define MTOT  (B_*NP)   // 18816
#define SLOTB 640       // slots per batch (48 ner + up to 148 pairs * 4)
#define MG    (B_*SLOTB) // 5120 gathered slots = 40 tiles of 128
#define GSCALE 32.0f    // g0 -> fp8 pre-scale (avoids e4m3 denormal region)

typedef unsigned short u16;
typedef unsigned char  u8;
typedef __bf16 bf16x8 __attribute__((ext_vector_type(8)));
typedef float  f32x4  __attribute__((ext_vector_type(4)));

__device__ __forceinline__ u16 f2b(float f) {
  union { float f; unsigned u; } c; c.f = f;
  unsigned u = c.u;
  u += 0x7fffu + ((u >> 16) & 1u);           // round-to-nearest-even
  return (u16)(u >> 16);
}
__device__ __forceinline__ float b2f(u16 h) {
  union { unsigned u; float f; } c; c.u = ((unsigned)h) << 16;
  return c.f;
}
// ---- e4m3fn (OCP) encode/decode, hand-rolled (no header dependency) ----
__device__ __forceinline__ u8 f2f8(float f) {
  unsigned u = __float_as_uint(f);
  u8 s = (u >> 24) & 0x80;
  float a = fabsf(f);
  if (a < 0.0009765625f) return s;            // < 2^-10 -> 0
  if (a >= 448.f) return s | 0x7E;            // clamp to max finite 448
  int e = ((u >> 23) & 0xFF) - 127;
  if (e < -6) {                               // denormal: m * 2^-9
    int q = (int)(a * 512.f + 0.5f);
    if (q >= 8) return s | 0x08;
    return s | (u8)q;
  }
  float sc = __uint_as_float((unsigned)((127 - e) << 23));   // 2^-e
  int q = (int)(a * sc * 8.f + 0.5f);          // 8..16
  if (q >= 16) { q = 8; ++e; if (e > 8) return s | 0x7E; }
  return s | (u8)(((e + 7) << 3) | (q - 8));
}
__device__ __forceinline__ float f82f(u8 v) {
  unsigned s = ((unsigned)(v & 0x80u)) << 24;
  unsigned e = (v >> 3) & 0xF, m = v & 7;
  if (e == 0) {
    if (m == 0) return __uint_as_float(s);
    float f = (float)m * 0.001953125f;         // m * 2^-9
    return __uint_as_float(s | __float_as_uint(f));
  }
  return __uint_as_float(s | ((e + 120u) << 23) | (m << 20));
}
__device__ __forceinline__ void gload16(const void* g, void* lds) {
  __builtin_amdgcn_global_load_lds(
      (const __attribute__((address_space(1))) unsigned*)g,
      (__attribute__((address_space(3))) unsigned*)lds, 16, 0, 0);
}

// ----------------------------------------------------------------- zero ----
__global__ void zero_zp(u16* zp) { zp[threadIdx.x] = 0; }

// ------------------------------------------------------------- prep_adj ----
// adj f32 -> fp8 e4m3 (same layout) + rdenom = 1/(rowsum+1).
__global__ __launch_bounds__(256) void prep_adj(const float* __restrict__ adj,
                                                u8* __restrict__ adj8,
                                                float* __restrict__ rdenom) {
  const int row = blockIdx.x;                 // 0..18815
  const float4* src = (const float4*)(adj + (size_t)row * NP);
  u8* dst = adj8 + (size_t)row * NP;
  float s = 0.f;
  for (int i = threadIdx.x; i < NP / 4; i += 256) {
    float4 v = src[i];
    s += (v.x + v.y) + (v.z + v.w);
    uchar4 o; o.x = f2f8(v.x); o.y = f2f8(v.y); o.z = f2f8(v.z); o.w = f2f8(v.w);
    *(uchar4*)(dst + i * 4) = o;
  }
  #pragma unroll
  for (int o = 32; o > 0; o >>= 1) s += __shfl_down(s, o, 64);
  __shared__ float red[4];
  int w = threadIdx.x >> 6, l = threadIdx.x & 63;
  if (l == 0) red[w] = s;
  __syncthreads();
  if (threadIdx.x == 0)
    rdenom[row] = 1.f / (red[0] + red[1] + red[2] + red[3] + 1.f);
}

// ------------------------------------------------------------- pair_prep ---
__global__ __launch_bounds__(512) void pair_prep(const int* __restrict__ ps,
                                                 const int* __restrict__ hs,
                                                 const int* __restrict__ ts,
                                                 const float* __restrict__ rdenom,
                                                 int* __restrict__ rowmap,
                                                 int* __restrict__ pslot,
                                                 float* __restrict__ rdenom_g) {
  __shared__ int sps[PAIRS];
  const int t = threadIdx.x;
  sps[t] = ps[t];
  for (int i = t; i < MG; i += 512) rowmap[i] = 0;
  __syncthreads();
  if (t < B_ * SENT) {                       // ner slots
    int b = t / SENT, j = t % SENT;
    rowmap[b * SLOTB + j] = j;
  }
  const int b = sps[t];
  int rank = 0;
  for (int q = 0; q < t; ++q) rank += (sps[q] == b) ? 1 : 0;
  const int h = hs[t], tt = ts[t];
  const int s0 = b * SLOTB + SENT + 4 * rank;
  rowmap[s0 + 0] = (h + 1) * SENT + tt;
  rowmap[s0 + 1] = (h + 1) * SENT + tt + 1;
  rowmap[s0 + 2] = (h + 2) * SENT + tt;
  rowmap[s0 + 3] = (h + 2) * SENT + tt + 1;
  pslot[t] = s0;
  __syncthreads();
  for (int i = t; i < MG; i += 512)
    rdenom_g[i] = rdenom[(i / SLOTB) * NP + rowmap[i]];
}

// ----------------------------------------------------- transpose-convert ---
// in [R][C] f32 -> out [C][R] (bf16 or fp8).  64x64 tiles, 256 threads.
template<int OUT8>
__global__ __launch_bounds__(256) void tcvt(const float* __restrict__ in_,
                                            void* __restrict__ out,
                                            int R, int C, size_t inb, size_t outb) {
  __shared__ u16 tile[64][65];
  const int b  = blockIdx.z;
  const int r0 = blockIdx.x * 64, c0 = blockIdx.y * 64;
  const int t  = threadIdx.x;
  const int tr = t >> 4, tc = (t & 15) * 4;
  #pragma unroll
  for (int i = 0; i < 4; ++i) {
    int rl = i * 16 + tr;
    int r  = r0 + rl;
    if (r < R) {
      const float* in = in_ + (size_t)b * inb + (size_t)r * C + c0 + tc;
      float4 v = *(const float4*)in;
      tile[rl][tc + 0] = f2b(v.x); tile[rl][tc + 1] = f2b(v.y);
      tile[rl][tc + 2] = f2b(v.z); tile[rl][tc + 3] = f2b(v.w);
    }
  }
  __syncthreads();
  const int c  = t >> 2;
  const int rb = (t & 3) * 16;
  #pragma unroll
  for (int i = 0; i < 4; ++i) {
    int rl = rb + i * 4;
    int r  = r0 + rl;
    if (OUT8) {
      u8* orow = (u8*)out + (size_t)b * outb + (size_t)(c0 + c) * R + r0;
      if (r + 3 < R) {
        uchar4 v;
        v.x = f2f8(b2f(tile[rl + 0][c])); v.y = f2f8(b2f(tile[rl + 1][c]));
        v.z = f2f8(b2f(tile[rl + 2][c])); v.w = f2f8(b2f(tile[rl + 3][c]));
        *(uchar4*)(orow + rl) = v;
      } else {
        for (int j = 0; j < 4; ++j)
          if (r + j < R) orow[rl + j] = f2f8(b2f(tile[rl + j][c]));
      }
    } else {
      u16* orow = (u16*)out + (size_t)b * outb + (size_t)(c0 + c) * R + r0;
      if (r + 3 < R) {
        ushort4 v;
        v.x = tile[rl + 0][c]; v.y = tile[rl + 1][c];
        v.z = tile[rl + 2][c]; v.w = tile[rl + 3][c];
        *(ushort4*)(orow + rl) = v;
      } else {
        for (int j = 0; j < 4; ++j)
          if (r + j < R) orow[rl + j] = tile[rl + j][c];
      }
    }
  }
}

// ------------------------------------------- 4-wave 128x128 GEMM core ------
// R8/R11 structure: BM=BN=128, BK=64, dbuf-2, T3-min schedule, both-sides
// 16B-chunk swizzle, zero-page K-tail, 2+ blocks/CU.
// MODE 0 runs in FP8 e4m3 (A=adj8, B=x^T8 or g0^T8*32): halves staging
// loads (8->4/thread/tile), LDS bytes (64->32KB), and HBM A/B traffic.
// Epilogue: acc*ascale + residual (residual: x^T fp8 via B buffer, or g0
// bf16 row-major via Xt when GATHER).
// MODE 1: (S@W + 2b)*rdenom, relu (bf16); WRITE_T also emits g0^T fp8 *32.
// MODE 2: concat(g0,g1)@outw + b (bf16; GATHER gathers the g0 half).
template<int MODE, int WRITE_T, int GATHER>
__global__ __launch_bounds__(256, 2) void gemm8(
    const void* __restrict__ A, const void* __restrict__ A2,
    const void* __restrict__ Bm, const u16* __restrict__ Xt,
    const float* __restrict__ bias, const float* __restrict__ rdenom,
    const int* __restrict__ rowmap,
    const u16* __restrict__ zp, u16* __restrict__ out, u8* __restrict__ outT,
    float ascale)
{
  constexpr bool F8   = (MODE == 0);
  constexpr int KACT   = (MODE == 0) ? NP : (MODE == 1 ? 512 : 1024);
  constexpr int KTILES = (KACT + 63) / 64;     // 37 / 8 / 16
  constexpr int EPC    = F8 ? 16 : 8;          // elements per 16B chunk
  constexpr int CPT    = F8 ? 4 : 8;           // chunks per row per K-tile
  constexpr int NJ     = F8 ? 2 : 4;           // stage issues per thread
  constexpr int ABYTES = F8 ? 8192 : 16384;    // bytes per dbuf per operand

  int m0, n0, bat = 0;
  const u8* Ab = (const u8*)A;
  const u8* Bb = (const u8*)Bm;
  size_t outBase = 0;
  if constexpr (GATHER) {
    // grid 160 = 8 XCDs x 20; 40 m-tiles (5/batch) x 4 n-tiles
    const int bx  = blockIdx.x;
    const int rid = (bx & 7) * 20 + (bx >> 3);
    const int mt  = rid >> 2;                 // 0..39
    n0 = (rid & 3) << 7;
    m0 = mt * 128;                            // slot-space
    bat = mt / 5;
    if constexpr (MODE == 0) {
      Ab = (const u8*)A  + (size_t)bat * NP * NP;       // adj8
      Bb = (const u8*)Bm + (size_t)bat * 512 * NP;      // g0t8
    }
  } else if constexpr (MODE == 0) {
    // grid 608 = 8 XCD chunks x 76 (one batch per chunk); 19 m x 4 n
    const int bx  = blockIdx.x;
    bat = bx & 7;
    const int loc = bx >> 3;                  // 0..75
    const int mt  = loc >> 2;                 // 0..18
    n0 = (loc & 3) << 7;
    m0 = (mt < 18) ? mt * 128 : NP - 128;     // overlap last tile
    Ab = (const u8*)A  + (size_t)bat * NP * NP;
    Bb = (const u8*)Bm + (size_t)bat * 512 * NP;
    outBase = (size_t)bat * NP * 512;
  } else {
    // grid 588 = 147 m x 4 n; bijective XCD chunking (q=73, r=4)
    const int bx  = blockIdx.x;
    const int xcd = bx & 7, pos = bx >> 3;
    const int rid = (xcd < 4) ? xcd * 74 + pos : 296 + (xcd - 4) * 73 + pos;
    const int mt  = rid >> 2;                 // 0..146
    n0 = (rid & 3) << 7;
    m0 = mt * 128;                            // exact (147*128 = 18816)
  }

  // [dbuf][(slab)][128 rows][chunks x 16B]; row stride 64B in BOTH formats
  __shared__ __align__(16) u8 As[2 * ABYTES];
  __shared__ __align__(16) u8 Bs[2 * ABYTES];

  const int tid = threadIdx.x;
  const int l  = tid & 63;
  const int w  = tid >> 6;
  const int wm = w >> 1, wn = w & 1;
  const int lr = l & 15, lq = l >> 4;

  f32x4 acc[4][4];
  #pragma unroll
  for (int i = 0; i < 4; ++i)
    #pragma unroll
    for (int j = 0; j < 4; ++j)
      acc[i][j] = (f32x4){0.f, 0.f, 0.f, 0.f};

  // Two staged rows per thread (row tid>>2 and 64+tid>>2), gathered where
  // A is indexed in original row space (MODE 0 adj rows, MODE 2 g0 half).
  int rsrc[2];
  #pragma unroll
  for (int j = 0; j < 2; ++j) {
    const int row = j * 64 + (tid >> 2);
    if constexpr (GATHER && MODE != 1) rsrc[j] = rowmap[m0 + row];
    else                               rsrc[j] = m0 + row;
  }

  auto STAGE = [&](int isA, int d, int kt) {
    #pragma unroll
    for (int j = 0; j < NJ; ++j) {
      const int cl   = j * 256 + tid;
      const int row  = (cl >> 2) & 127;
      const int slot = cl & 3;
      const int s    = F8 ? 0 : (cl >> 9);
      const int gch  = kt * CPT + s * 4 + (slot ^ ((row >> 1) & 3));
      const u8* src;
      if (isA) {
        if constexpr (MODE == 0) {
          src = Ab + (size_t)rsrc[j & 1] * NP + (size_t)gch * 16;
        } else if constexpr (MODE == 1) {
          src = (const u8*)A + ((size_t)(m0 + row) * 512 + (size_t)gch * 8) * 2;
        } else {   // MODE 2: concat(g0, g1) over k
          int rg = (GATHER ? rsrc[j & 1] : (m0 + row));
          src = (gch < 64)
              ? (const u8*)A  + (((size_t)(GATHER ? bat * NP : 0) + rg) * 512
                                 + (size_t)gch * 8) * 2
              : (const u8*)A2 + ((size_t)(m0 + row) * 512
                                 + (size_t)(gch - 64) * 8) * 2;
        }
        if (gch * EPC + EPC > KACT) src = (const u8*)zp;
        gload16(src, As + d * ABYTES + cl * 16);
      } else {
        if constexpr (F8)
          src = Bb + (size_t)(n0 + row) * NP + (size_t)gch * 16;
        else
          src = (const u8*)Bm + ((size_t)(n0 + row) * KACT + (size_t)gch * 8) * 2;
        if (gch * EPC + EPC > KACT) src = (const u8*)zp;
        gload16(src, Bs + d * ABYTES + cl * 16);
      }
    }
  };

  // prologue: tile 0 into buf 0
  STAGE(1, 0, 0);
  STAGE(0, 0, 0);
  asm volatile("s_waitcnt vmcnt(0)" ::: "memory");
  __builtin_amdgcn_s_barrier();

  int d = 0;
  for (int kt = 0; kt < KTILES; ++kt) {
    if (kt + 1 < KTILES) {
      STAGE(1, d ^ 1, kt + 1);
      STAGE(0, d ^ 1, kt + 1);
    }
    const u8* Ad = As + d * ABYTES;
    const u8* Bd = Bs + d * ABYTES;
    if constexpr (F8) {
      long a0[4], b0[4], a1[4], b1[4];
      #pragma unroll
      for (int f = 0; f < 4; ++f) {
        const int ra = wm * 64 + f * 16 + lr;
        const int rb = wn * 64 + f * 16 + lr;
        const int swa = (ra >> 1) & 3, swb = (rb >> 1) & 3;
        const int co = (lq >> 1), bo = (lq & 1) << 3;
        a0[f] = *(const long*)(Ad + ra * 64 + (((0 + co) ^ swa) << 4) + bo);
        b0[f] = *(const long*)(Bd + rb * 64 + (((0 + co) ^ swb) << 4) + bo);
        a1[f] = *(const long*)(Ad + ra * 64 + (((2 + co) ^ swa) << 4) + bo);
        b1[f] = *(const long*)(Bd + rb * 64 + (((2 + co) ^ swb) << 4) + bo);
      }
      asm volatile("s_waitcnt lgkmcnt(0)" ::: "memory");
      __builtin_amdgcn_sched_barrier(0);
      __builtin_amdgcn_s_setprio(1);
      #pragma unroll
      for (int mf = 0; mf < 4; ++mf)
        #pragma unroll
        for (int nf = 0; nf < 4; ++nf)
          acc[mf][nf] = __builtin_amdgcn_mfma_f32_16x16x32_fp8_fp8(
              a0[mf], b0[nf], acc[mf][nf], 0, 0, 0);
      #pragma unroll
      for (int mf = 0; mf < 4; ++mf)
        #pragma unroll
        for (int nf = 0; nf < 4; ++nf)
          acc[mf][nf] = __builtin_amdgcn_mfma_f32_16x16x32_fp8_fp8(
              a1[mf], b1[nf], acc[mf][nf], 0, 0, 0);
      __builtin_amdgcn_s_setprio(0);
      __builtin_amdgcn_sched_barrier(0);
    } else {
      bf16x8 a0[4], b0[4], a1[4], b1[4];
      #pragma unroll
      for (int f = 0; f < 4; ++f) {
        const int ra = wm * 64 + f * 16 + lr;
        const int rb = wn * 64 + f * 16 + lr;
        const int sa = (lq ^ ((ra >> 1) & 3)) << 4;
        const int sb = (lq ^ ((rb >> 1) & 3)) << 4;
        a0[f] = *(const bf16x8*)(Ad + ra * 64 + sa);
        b0[f] = *(const bf16x8*)(Bd + rb * 64 + sb);
        a1[f] = *(const bf16x8*)(Ad + 8192 + ra * 64 + sa);
        b1[f] = *(const bf16x8*)(Bd + 8192 + rb * 64 + sb);
      }
      asm volatile("s_waitcnt lgkmcnt(0)" ::: "memory");
      __builtin_amdgcn_sched_barrier(0);
      __builtin_amdgcn_s_setprio(1);
      #pragma unroll
      for (int mf = 0; mf < 4; ++mf)
        #pragma unroll
        for (int nf = 0; nf < 4; ++nf)
          acc[mf][nf] = __builtin_amdgcn_mfma_f32_16x16x32_bf16(
              a0[mf], b0[nf], acc[mf][nf], 0, 0, 0);
      #pragma unroll
      for (int mf = 0; mf < 4; ++mf)
        #pragma unroll
        for (int nf = 0; nf < 4; ++nf)
          acc[mf][nf] = __builtin_amdgcn_mfma_f32_16x16x32_bf16(
              a1[mf], b1[nf], acc[mf][nf], 0, 0, 0);
      __builtin_amdgcn_s_setprio(0);
      __builtin_amdgcn_sched_barrier(0);
    }
    asm volatile("s_waitcnt vmcnt(0)" ::: "memory");  // next tile landed
    __builtin_amdgcn_s_barrier();
    d ^= 1;
  }

  // --------------------------------------------------------- epilogue ----
  #pragma unroll
  for (int mf = 0; mf < 4; ++mf) {
    const int gm0 = m0 + wm * 64 + mf * 16 + lq * 4;
    f32x4 rd;
    if constexpr (MODE == 1) rd = *(const f32x4*)(rdenom + gm0);
    int rsm[4];
    if constexpr (GATHER && MODE == 0) {
      #pragma unroll
      for (int r = 0; r < 4; ++r) rsm[r] = rowmap[gm0 + r];
    }
    #pragma unroll
    for (int nf = 0; nf < 4; ++nf) {
      const int gn = n0 + wn * 64 + nf * 16 + lr;
      float vf[4];
      if constexpr (MODE == 0) {
        float xf[4];
        if constexpr (GATHER) {
          #pragma unroll
          for (int r = 0; r < 4; ++r)
            xf[r] = b2f(Xt[((size_t)bat * NP + rsm[r]) * 512 + gn]);
        } else {
          uchar4 xv = *(const uchar4*)(Bb + (size_t)gn * NP + gm0);
          xf[0] = f82f(xv.x); xf[1] = f82f(xv.y);
          xf[2] = f82f(xv.z); xf[3] = f82f(xv.w);
        }
        #pragma unroll
        for (int r = 0; r < 4; ++r) vf[r] = acc[mf][nf][r] * ascale + xf[r];
      } else if constexpr (MODE == 1) {
        const float bn = 2.f * bias[gn];
        #pragma unroll
        for (int r = 0; r < 4; ++r)
          vf[r] = fmaxf((acc[mf][nf][r] + bn) * rd[r], 0.f);
      } else {
        const float bn = bias[gn];
        #pragma unroll
        for (int r = 0; r < 4; ++r) vf[r] = acc[mf][nf][r] + bn;
      }
      #pragma unroll
      for (int r = 0; r < 4; ++r)
        out[outBase + (size_t)(gm0 + r) * 512 + gn] = f2b(vf[r]);
      if constexpr (WRITE_T) {
        const int bb = gm0 / NP;               // quad never straddles batch
        const int ml = gm0 - bb * NP;
        uchar4 tv;
        tv.x = f2f8(vf[0] * GSCALE); tv.y = f2f8(vf[1] * GSCALE);
        tv.z = f2f8(vf[2] * GSCALE); tv.w = f2f8(vf[3] * GSCALE);
        *(uchar4*)(outT + ((size_t)bb * 512 + gn) * NP + ml) = tv;
      }
    }
  }
}

// ------------------------------------------------------------- ner head ----
__global__ __launch_bounds__(64) void ner_kernel(const float* __restrict__ ner,
                                                 const u16* __restrict__ logits_g,
                                                 const float* __restrict__ nw,
                                                 const float* __restrict__ nb,
                                                 float* __restrict__ out) {
  int r = blockIdx.x;                 // 0..383
  int b = r / SENT, tp = r % SENT;
  int lane = threadIdx.x;
  const float* nrow = ner      + ((size_t)b * SENT  + tp) * D_;
  const u16*   lrow = logits_g + ((size_t)b * SLOTB + tp) * D_;
  float rv[16];
  #pragma unroll
  for (int i = 0; i < 8; ++i) rv[i]     = nrow[lane + i * 64];
  #pragma unroll
  for (int i = 0; i < 8; ++i) rv[8 + i] = b2f(lrow[lane + i * 64]);
  for (int j = 0; j < NERL; ++j) {
    float s = 0.f;
    #pragma unroll
    for (int i = 0; i < 16; ++i)
      s = fmaf(rv[i], nw[(size_t)(lane + i * 64) * NERL + j], s);
    for (int o = 32; o > 0; o >>= 1) s += __shfl_down(s, o);
    if (lane == 0) out[r * NERL + j] = s + nb[j];
  }
}

// ----------------------------------------------------------- pair + re -----
__global__ __launch_bounds__(256) void pair_kernel(const u16* __restrict__ logits_g,
                                                   const float* __restrict__ refeat,
                                                   const float* __restrict__ rw,
                                                   const float* __restrict__ rb,
                                                   const int* __restrict__ pslot,
                                                   float* __restrict__ out) {
  int p = blockIdx.x;
  __shared__ float avg[D_];
  const u16* r0 = logits_g + (size_t)pslot[p] * D_;   // 4 consecutive slots
  for (int dd = threadIdx.x; dd < D_; dd += 256)
    avg[dd] = 0.25f * (b2f(r0[dd]) + b2f(r0[D_ + dd]) +
                       b2f(r0[2 * D_ + dd]) + b2f(r0[3 * D_ + dd]));
  __syncthreads();
  int wave = threadIdx.x >> 6, lane = threadIdx.x & 63;
  const float* rf = refeat + (size_t)p * D_;
  for (int jj = 0; jj < 8; ++jj) {
    int j = wave * 8 + jj;
    float s = 0.f;
    #pragma unroll
    for (int i = 0; i < 8; ++i) {
      int k = lane + i * 64;
      s = fmaf(rf[k],  rw[(size_t)k * REL + j], s);
      s = fmaf(avg[k], rw[(size_t)(k + D_) * REL + j], s);
    }
    for (int o = 32; o > 0; o >>= 1) s += __shfl_down(s, o);
    if (lane == 0) out[p * REL + j] = s + rb[j];
  }
}

// --------------------------------------------------------------- launch ----
extern "C" void kernel_launch(void* const* d_in, const int* in_sizes, int n_in,
                              void* d_out, int out_size, void* d_ws, size_t ws_size,
                              hipStream_t stream) {
  const float* inputs = (const float*)d_in[0];
  const float* ner    = (const float*)d_in[1];
  const float* refeat = (const float*)d_in[2];
  const float* adj    = (const float*)d_in[3];
  const float* W0w    = (const float*)d_in[4];
  const float* W0b    = (const float*)d_in[5];
  const float* W1w    = (const float*)d_in[6];
  const float* W1b    = (const float*)d_in[7];
  const float* outw   = (const float*)d_in[8];
  const float* outb   = (const float*)d_in[9];
  const float* nerw   = (const float*)d_in[10];
  const float* nerb   = (const float*)d_in[11];
  const float* rew    = (const float*)d_in[12];
  const float* reb    = (const float*)d_in[13];
  const int*   ps     = (const int*)d_in[14];
  const int*   hs     = (const int*)d_in[15];
  const int*   ts     = (const int*)d_in[16];
  (void)in_sizes; (void)n_in; (void)out_size; (void)ws_size;
  float* outp = (float*)d_out;

  char* ws = (char*)d_ws;
  size_t off = 0;
  u8* adj8 = (u8*)(ws + off); off += (size_t)B_ * NP * NP;        // 44.3 MB
  float* rdenom = (float*)(ws + off); off += (size_t)MTOT * 4;
  u16* zp  = (u16*)(ws + off); off += 1024;
  u16* w0t = (u16*)(ws + off); off += 512 * 512 * 2;
  u16* w1t = (u16*)(ws + off); off += 512 * 512 * 2;
  u16* owt = (u16*)(ws + off); off += 512 * 1024 * 2;
  u8*  xt8 = (u8*)(ws + off); off += (size_t)B_ * 512 * NP;       // x^T8 / g0^T8
  u16* S   = (u16*)(ws + off); off += (size_t)MTOT * 512 * 2;
  u16* g0  = (u16*)(ws + off); off += (size_t)MTOT * 512 * 2;
  int* rowmap = (int*)(ws + off); off += (size_t)MG * 4;
  int* pslot  = (int*)(ws + off); off += (size_t)PAIRS * 4;
  float* rdenom_g = (float*)(ws + off); off += (size_t)MG * 4;
  u16* S_g      = (u16*)(ws + off); off += (size_t)MG * 512 * 2;
  u16* g1_g     = (u16*)(ws + off); off += (size_t)MG * 512 * 2;
  u16* logits_g = (u16*)(ws + off); off += (size_t)MG * 512 * 2;

  zero_zp<<<1, 512, 0, stream>>>(zp);
  prep_adj<<<MTOT, 256, 0, stream>>>(adj, adj8, rdenom);
  pair_prep<<<1, 512, 0, stream>>>(ps, hs, ts, rdenom, rowmap, pslot, rdenom_g);

  dim3 gT((NP + 63) / 64, D_ / 64, B_);         // (37, 8, 8)
  tcvt<1><<<gT, 256, 0, stream>>>(inputs, xt8, NP, D_,
                                  (size_t)NP * D_, (size_t)D_ * NP);
  tcvt<0><<<dim3(8, 8, 1),  256, 0, stream>>>(W0w,  w0t, 512,  512, 0, 0);
  tcvt<0><<<dim3(8, 8, 1),  256, 0, stream>>>(W1w,  w1t, 512,  512, 0, 0);
  tcvt<0><<<dim3(16, 8, 1), 256, 0, stream>>>(outw, owt, 1024, 512, 0, 0);

  // Layer 1: S = adj@x + x (fp8); g0 = relu((S@W0+2b)/denom) (+ g0^T fp8*32)
  gemm8<0,0,0><<<608, 256, 0, stream>>>(adj8, nullptr, xt8, nullptr,
                                        nullptr, nullptr, nullptr, zp, S,
                                        nullptr, 1.0f);
  gemm8<1,1,0><<<588, 256, 0, stream>>>(S, nullptr, w0t, nullptr,
                                        W0b, rdenom, nullptr, zp, g0,
                                        xt8, 1.0f);
  // Layer 2 (gathered, M = 5120 slots)
  gemm8<0,0,1><<<160, 256, 0, stream>>>(adj8, nullptr, xt8, g0,
                                        nullptr, nullptr, rowmap, zp, S_g,
                                        nullptr, 1.0f / GSCALE);
  gemm8<1,0,1><<<160, 256, 0, stream>>>(S_g, nullptr, w1t, nullptr,
                                        W1b, rdenom_g, rowmap, zp, g1_g,
                                        nullptr, 1.0f);
  gemm8<2,0,1><<<160, 256, 0, stream>>>(g0, g1_g, owt, nullptr,
                                        outb, nullptr, rowmap, zp, logits_g,
                                        nullptr, 1.0f);

  ner_kernel <<<B_ * SENT, 64,  0, stream>>>(ner, logits_g, nerw, nerb, outp);
  pair_kernel<<<PAIRS,     256, 0, stream>>>(logits_g, refeat, rew, reb, pslot,
                                             outp + B_ * SENT * NERL);
}

// Round 14
// 326.540 us; speedup vs baseline: 1.2010x; 1.1029x over previous
//
#include <hip/hip_runtime.h>
#include <hip/hip_bf16.h>

#define B_    8
#define NP    2352
#define D_    512
#define SENT  48
#define PAIRS 512
#define NERL  16
#define REL   32
#define MTOT  (B_*NP)   // 18816
#define SLOTB 640       // slots per batch (48 ner + up to 148 pairs * 4)
#define MG    (B_*SLOTB) // 5120 gathered slots = 40 tiles of 128
#define GSCALE 32.0f    // g0 -> fp8 pre-scale (avoids e4m3 denormal region)

typedef unsigned short u16;
typedef unsigned char  u8;
typedef __bf16 bf16x8 __attribute__((ext_vector_type(8)));
typedef float  f32x4  __attribute__((ext_vector_type(4)));

__device__ __forceinline__ u16 f2b(float f) {
  union { float f; unsigned u; } c; c.f = f;
  unsigned u = c.u;
  u += 0x7fffu + ((u >> 16) & 1u);           // round-to-nearest-even
  return (u16)(u >> 16);
}
__device__ __forceinline__ float b2f(u16 h) {
  union { unsigned u; float f; } c; c.u = ((unsigned)h) << 16;
  return c.f;
}
// ---- e4m3fn (OCP) encode/decode, hand-rolled ----
__device__ __forceinline__ u8 f2f8(float f) {
  unsigned u = __float_as_uint(f);
  u8 s = (u >> 24) & 0x80;
  float a = fabsf(f);
  if (a < 0.0009765625f) return s;            // < 2^-10 -> 0
  if (a >= 448.f) return s | 0x7E;            // clamp to max finite 448
  int e = ((u >> 23) & 0xFF) - 127;
  if (e < -6) {                               // denormal: m * 2^-9
    int q = (int)(a * 512.f + 0.5f);
    if (q >= 8) return s | 0x08;
    return s | (u8)q;
  }
  float sc = __uint_as_float((unsigned)((127 - e) << 23));   // 2^-e
  int q = (int)(a * sc * 8.f + 0.5f);          // 8..16
  if (q >= 16) { q = 8; ++e; if (e > 8) return s | 0x7E; }
  return s | (u8)(((e + 7) << 3) | (q - 8));
}
__device__ __forceinline__ float f82f(u8 v) {
  unsigned s = ((unsigned)(v & 0x80u)) << 24;
  unsigned e = (v >> 3) & 0xF, m = v & 7;
  if (e == 0) {
    if (m == 0) return __uint_as_float(s);
    float f = (float)m * 0.001953125f;         // m * 2^-9
    return __uint_as_float(s | __float_as_uint(f));
  }
  return __uint_as_float(s | ((e + 120u) << 23) | (m << 20));
}
__device__ __forceinline__ void gload16(const void* g, void* lds) {
  __builtin_amdgcn_global_load_lds(
      (const __attribute__((address_space(1))) unsigned*)g,
      (__attribute__((address_space(3))) unsigned*)lds, 16, 0, 0);
}

// ----------------------------------------------------- transpose-convert ---
// in [R][C] f32 -> out [C][R] (bf16 or fp8), one 64x64 tile.
template<int OUT8>
__device__ __forceinline__ void tcvt_body(const float* __restrict__ in_,
                                          void* __restrict__ out,
                                          int R, int C, int b, int r0, int c0,
                                          size_t inb, size_t outb,
                                          u16 tile[64][65]) {
  const int t  = threadIdx.x;
  const int tr = t >> 4, tc = (t & 15) * 4;
  #pragma unroll
  for (int i = 0; i < 4; ++i) {
    int rl = i * 16 + tr;
    int r  = r0 + rl;
    if (r < R) {
      const float* in = in_ + (size_t)b * inb + (size_t)r * C + c0 + tc;
      float4 v = *(const float4*)in;
      tile[rl][tc + 0] = f2b(v.x); tile[rl][tc + 1] = f2b(v.y);
      tile[rl][tc + 2] = f2b(v.z); tile[rl][tc + 3] = f2b(v.w);
    }
  }
  __syncthreads();
  const int c  = t >> 2;
  const int rb = (t & 3) * 16;
  #pragma unroll
  for (int i = 0; i < 4; ++i) {
    int rl = rb + i * 4;
    int r  = r0 + rl;
    if (OUT8) {
      u8* orow = (u8*)out + (size_t)b * outb + (size_t)(c0 + c) * R + r0;
      if (r + 3 < R) {
        uchar4 v;
        v.x = f2f8(b2f(tile[rl + 0][c])); v.y = f2f8(b2f(tile[rl + 1][c]));
        v.z = f2f8(b2f(tile[rl + 2][c])); v.w = f2f8(b2f(tile[rl + 3][c]));
        *(uchar4*)(orow + rl) = v;
      } else {
        for (int j = 0; j < 4; ++j)
          if (r + j < R) orow[rl + j] = f2f8(b2f(tile[rl + j][c]));
      }
    } else {
      u16* orow = (u16*)out + (size_t)b * outb + (size_t)(c0 + c) * R + r0;
      if (r + 3 < R) {
        ushort4 v;
        v.x = tile[rl + 0][c]; v.y = tile[rl + 1][c];
        v.z = tile[rl + 2][c]; v.w = tile[rl + 3][c];
        *(ushort4*)(orow + rl) = v;
      } else {
        for (int j = 0; j < 4; ++j)
          if (r + j < R) orow[rl + j] = tile[rl + j][c];
      }
    }
  }
}

// -------------------------------------------------------------- fat prep ---
// One dispatch covering all independent preprocessing:
//  blocks [0, MTOT)        : adj f32 -> fp8 + rowsum -> rdenom (one row each)
//  block  MTOT             : zero the zero-page
//  block  MTOT+1           : rowmap/pslot build (deterministic ranks)
//  blocks [MTOT+2, +2368)  : x^T fp8 tcvt (37x8 tiles x 8 batches)
//  next 64 / 64 / 128      : W0^T, W1^T, outw^T bf16 tcvt
__global__ __launch_bounds__(256) void fat_prep(
    const float* __restrict__ adj, const float* __restrict__ inputs,
    const float* __restrict__ W0w, const float* __restrict__ W1w,
    const float* __restrict__ outw,
    const int* __restrict__ ps, const int* __restrict__ hs,
    const int* __restrict__ ts,
    u8* __restrict__ adj8, float* __restrict__ rdenom,
    u8* __restrict__ xt8, u16* __restrict__ w0t, u16* __restrict__ w1t,
    u16* __restrict__ owt, int* __restrict__ rowmap, int* __restrict__ pslot,
    u16* __restrict__ zp) {
  __shared__ u16 tile[64][65];
  __shared__ int sps[PAIRS];
  __shared__ float red[4];
  const int bx = blockIdx.x;
  const int t  = threadIdx.x;

  if (bx < MTOT) {                            // ---- prep_adj row
    const int row = bx;
    const float4* src = (const float4*)(adj + (size_t)row * NP);
    u8* dst = adj8 + (size_t)row * NP;
    float s = 0.f;
    for (int i = t; i < NP / 4; i += 256) {
      float4 v = src[i];
      s += (v.x + v.y) + (v.z + v.w);
      uchar4 o; o.x = f2f8(v.x); o.y = f2f8(v.y);
      o.z = f2f8(v.z); o.w = f2f8(v.w);
      *(uchar4*)(dst + i * 4) = o;
    }
    #pragma unroll
    for (int o = 32; o > 0; o >>= 1) s += __shfl_down(s, o, 64);
    int w = t >> 6, l = t & 63;
    if (l == 0) red[w] = s;
    __syncthreads();
    if (t == 0)
      rdenom[row] = 1.f / (red[0] + red[1] + red[2] + red[3] + 1.f);
  } else if (bx == MTOT) {                    // ---- zero page
    zp[t] = 0; zp[256 + t] = 0;
  } else if (bx == MTOT + 1) {                // ---- rowmap / pslot
    sps[t] = ps[t]; sps[256 + t] = ps[256 + t];
    for (int i = t; i < MG; i += 256) rowmap[i] = 0;
    __syncthreads();
    for (int u = t; u < B_ * SENT; u += 256)
      rowmap[(u / SENT) * SLOTB + (u % SENT)] = u % SENT;
    for (int p = t; p < PAIRS; p += 256) {
      const int b = sps[p];
      int rank = 0;
      for (int q = 0; q < p; ++q) rank += (sps[q] == b) ? 1 : 0;
      const int h = hs[p], tt = ts[p];
      const int s0 = b * SLOTB + SENT + 4 * rank;
      rowmap[s0 + 0] = (h + 1) * SENT + tt;
      rowmap[s0 + 1] = (h + 1) * SENT + tt + 1;
      rowmap[s0 + 2] = (h + 2) * SENT + tt;
      rowmap[s0 + 3] = (h + 2) * SENT + tt + 1;
      pslot[p] = s0;
    }
  } else {                                    // ---- tcvt region
    int r = bx - (MTOT + 2);
    if (r < 2368) {                           // x^T fp8: 296 tiles x 8 batches
      const int b = r / 296, rem = r % 296;
      const int rx = rem % 37, ry = rem / 37;
      tcvt_body<1>(inputs, xt8, NP, D_, b, rx * 64, ry * 64,
                   (size_t)NP * D_, (size_t)D_ * NP, tile);
    } else if ((r -= 2368) < 64) {            // W0^T bf16
      tcvt_body<0>(W0w, w0t, 512, 512, 0, (r % 8) * 64, (r / 8) * 64,
                   0, 0, tile);
    } else if ((r -= 64) < 64) {              // W1^T bf16
      tcvt_body<0>(W1w, w1t, 512, 512, 0, (r % 8) * 64, (r / 8) * 64,
                   0, 0, tile);
    } else {                                  // outw^T bf16 (1024x512)
      r -= 64;
      tcvt_body<0>(outw, owt, 1024, 512, 0, (r % 16) * 64, (r / 16) * 64,
                   0, 0, tile);
    }
  }
}

// ------------------------------------------- 4-wave 128x128 GEMM core ------
// R13 structure unchanged: BM=BN=128, BK=64, dbuf-2, T3-min schedule,
// both-sides 16B-chunk swizzle, zero-page K-tail, 2+ blocks/CU.
// MODE 0 fp8 e4m3 (A=adj8, B=x^T8/g0^T8*32); MODE 1/2 bf16.
// MODE 1 GATHER now gathers rdenom directly via rowmap (rdenom_g removed).
template<int MODE, int WRITE_T, int GATHER>
__global__ __launch_bounds__(256, 2) void gemm8(
    const void* __restrict__ A, const void* __restrict__ A2,
    const void* __restrict__ Bm, const u16* __restrict__ Xt,
    const float* __restrict__ bias, const float* __restrict__ rdenom,
    const int* __restrict__ rowmap,
    const u16* __restrict__ zp, u16* __restrict__ out, u8* __restrict__ outT,
    float ascale)
{
  constexpr bool F8   = (MODE == 0);
  constexpr int KACT   = (MODE == 0) ? NP : (MODE == 1 ? 512 : 1024);
  constexpr int KTILES = (KACT + 63) / 64;     // 37 / 8 / 16
  constexpr int EPC    = F8 ? 16 : 8;          // elements per 16B chunk
  constexpr int CPT    = F8 ? 4 : 8;           // chunks per row per K-tile
  constexpr int NJ     = F8 ? 2 : 4;           // stage issues per thread
  constexpr int ABYTES = F8 ? 8192 : 16384;    // bytes per dbuf per operand

  int m0, n0, bat = 0;
  const u8* Ab = (const u8*)A;
  const u8* Bb = (const u8*)Bm;
  size_t outBase = 0;
  if constexpr (GATHER) {
    // grid 160 = 8 XCDs x 20; 40 m-tiles (5/batch) x 4 n-tiles
    const int bx  = blockIdx.x;
    const int rid = (bx & 7) * 20 + (bx >> 3);
    const int mt  = rid >> 2;                 // 0..39
    n0 = (rid & 3) << 7;
    m0 = mt * 128;                            // slot-space
    bat = mt / 5;
    if constexpr (MODE == 0) {
      Ab = (const u8*)A  + (size_t)bat * NP * NP;       // adj8
      Bb = (const u8*)Bm + (size_t)bat * 512 * NP;      // g0t8
    }
  } else if constexpr (MODE == 0) {
    // grid 608 = 8 XCD chunks x 76 (one batch per chunk); 19 m x 4 n
    const int bx  = blockIdx.x;
    bat = bx & 7;
    const int loc = bx >> 3;                  // 0..75
    const int mt  = loc >> 2;                 // 0..18
    n0 = (loc & 3) << 7;
    m0 = (mt < 18) ? mt * 128 : NP - 128;     // overlap last tile
    Ab = (const u8*)A  + (size_t)bat * NP * NP;
    Bb = (const u8*)Bm + (size_t)bat * 512 * NP;
    outBase = (size_t)bat * NP * 512;
  } else {
    // grid 588 = 147 m x 4 n; bijective XCD chunking (q=73, r=4)
    const int bx  = blockIdx.x;
    const int xcd = bx & 7, pos = bx >> 3;
    const int rid = (xcd < 4) ? xcd * 74 + pos : 296 + (xcd - 4) * 73 + pos;
    const int mt  = rid >> 2;                 // 0..146
    n0 = (rid & 3) << 7;
    m0 = mt * 128;                            // exact (147*128 = 18816)
  }

  __shared__ __align__(16) u8 As[2 * ABYTES];
  __shared__ __align__(16) u8 Bs[2 * ABYTES];

  const int tid = threadIdx.x;
  const int l  = tid & 63;
  const int w  = tid >> 6;
  const int wm = w >> 1, wn = w & 1;
  const int lr = l & 15, lq = l >> 4;

  f32x4 acc[4][4];
  #pragma unroll
  for (int i = 0; i < 4; ++i)
    #pragma unroll
    for (int j = 0; j < 4; ++j)
      acc[i][j] = (f32x4){0.f, 0.f, 0.f, 0.f};

  int rsrc[2];
  #pragma unroll
  for (int j = 0; j < 2; ++j) {
    const int row = j * 64 + (tid >> 2);
    if constexpr (GATHER && MODE != 1) rsrc[j] = rowmap[m0 + row];
    else                               rsrc[j] = m0 + row;
  }

  auto STAGE = [&](int isA, int d, int kt) {
    #pragma unroll
    for (int j = 0; j < NJ; ++j) {
      const int cl   = j * 256 + tid;
      const int row  = (cl >> 2) & 127;
      const int slot = cl & 3;
      const int s    = F8 ? 0 : (cl >> 9);
      const int gch  = kt * CPT + s * 4 + (slot ^ ((row >> 1) & 3));
      const u8* src;
      if (isA) {
        if constexpr (MODE == 0) {
          src = Ab + (size_t)rsrc[j & 1] * NP + (size_t)gch * 16;
        } else if constexpr (MODE == 1) {
          src = (const u8*)A + ((size_t)(m0 + row) * 512 + (size_t)gch * 8) * 2;
        } else {   // MODE 2: concat(g0, g1) over k
          int rg = (GATHER ? rsrc[j & 1] : (m0 + row));
          src = (gch < 64)
              ? (const u8*)A  + (((size_t)(GATHER ? bat * NP : 0) + rg) * 512
                                 + (size_t)gch * 8) * 2
              : (const u8*)A2 + ((size_t)(m0 + row) * 512
                                 + (size_t)(gch - 64) * 8) * 2;
        }
        if (gch * EPC + EPC > KACT) src = (const u8*)zp;
        gload16(src, As + d * ABYTES + cl * 16);
      } else {
        if constexpr (F8)
          src = Bb + (size_t)(n0 + row) * NP + (size_t)gch * 16;
        else
          src = (const u8*)Bm + ((size_t)(n0 + row) * KACT + (size_t)gch * 8) * 2;
        if (gch * EPC + EPC > KACT) src = (const u8*)zp;
        gload16(src, Bs + d * ABYTES + cl * 16);
      }
    }
  };

  // prologue: tile 0 into buf 0
  STAGE(1, 0, 0);
  STAGE(0, 0, 0);
  asm volatile("s_waitcnt vmcnt(0)" ::: "memory");
  __builtin_amdgcn_s_barrier();

  int d = 0;
  for (int kt = 0; kt < KTILES; ++kt) {
    if (kt + 1 < KTILES) {
      STAGE(1, d ^ 1, kt + 1);
      STAGE(0, d ^ 1, kt + 1);
    }
    const u8* Ad = As + d * ABYTES;
    const u8* Bd = Bs + d * ABYTES;
    if constexpr (F8) {
      long a0[4], b0[4], a1[4], b1[4];
      #pragma unroll
      for (int f = 0; f < 4; ++f) {
        const int ra = wm * 64 + f * 16 + lr;
        const int rb = wn * 64 + f * 16 + lr;
        const int swa = (ra >> 1) & 3, swb = (rb >> 1) & 3;
        const int co = (lq >> 1), bo = (lq & 1) << 3;
        a0[f] = *(const long*)(Ad + ra * 64 + (((0 + co) ^ swa) << 4) + bo);
        b0[f] = *(const long*)(Bd + rb * 64 + (((0 + co) ^ swb) << 4) + bo);
        a1[f] = *(const long*)(Ad + ra * 64 + (((2 + co) ^ swa) << 4) + bo);
        b1[f] = *(const long*)(Bd + rb * 64 + (((2 + co) ^ swb) << 4) + bo);
      }
      asm volatile("s_waitcnt lgkmcnt(0)" ::: "memory");
      __builtin_amdgcn_sched_barrier(0);
      __builtin_amdgcn_s_setprio(1);
      #pragma unroll
      for (int mf = 0; mf < 4; ++mf)
        #pragma unroll
        for (int nf = 0; nf < 4; ++nf)
          acc[mf][nf] = __builtin_amdgcn_mfma_f32_16x16x32_fp8_fp8(
              a0[mf], b0[nf], acc[mf][nf], 0, 0, 0);
      #pragma unroll
      for (int mf = 0; mf < 4; ++mf)
        #pragma unroll
        for (int nf = 0; nf < 4; ++nf)
          acc[mf][nf] = __builtin_amdgcn_mfma_f32_16x16x32_fp8_fp8(
              a1[mf], b1[nf], acc[mf][nf], 0, 0, 0);
      __builtin_amdgcn_s_setprio(0);
      __builtin_amdgcn_sched_barrier(0);
    } else {
      bf16x8 a0[4], b0[4], a1[4], b1[4];
      #pragma unroll
      for (int f = 0; f < 4; ++f) {
        const int ra = wm * 64 + f * 16 + lr;
        const int rb = wn * 64 + f * 16 + lr;
        const int sa = (lq ^ ((ra >> 1) & 3)) << 4;
        const int sb = (lq ^ ((rb >> 1) & 3)) << 4;
        a0[f] = *(const bf16x8*)(Ad + ra * 64 + sa);
        b0[f] = *(const bf16x8*)(Bd + rb * 64 + sb);
        a1[f] = *(const bf16x8*)(Ad + 8192 + ra * 64 + sa);
        b1[f] = *(const bf16x8*)(Bd + 8192 + rb * 64 + sb);
      }
      asm volatile("s_waitcnt lgkmcnt(0)" ::: "memory");
      __builtin_amdgcn_sched_barrier(0);
      __builtin_amdgcn_s_setprio(1);
      #pragma unroll
      for (int mf = 0; mf < 4; ++mf)
        #pragma unroll
        for (int nf = 0; nf < 4; ++nf)
          acc[mf][nf] = __builtin_amdgcn_mfma_f32_16x16x32_bf16(
              a0[mf], b0[nf], acc[mf][nf], 0, 0, 0);
      #pragma unroll
      for (int mf = 0; mf < 4; ++mf)
        #pragma unroll
        for (int nf = 0; nf < 4; ++nf)
          acc[mf][nf] = __builtin_amdgcn_mfma_f32_16x16x32_bf16(
              a1[mf], b1[nf], acc[mf][nf], 0, 0, 0);
      __builtin_amdgcn_s_setprio(0);
      __builtin_amdgcn_sched_barrier(0);
    }
    asm volatile("s_waitcnt vmcnt(0)" ::: "memory");  // next tile landed
    __builtin_amdgcn_s_barrier();
    d ^= 1;
  }

  // --------------------------------------------------------- epilogue ----
  #pragma unroll
  for (int mf = 0; mf < 4; ++mf) {
    const int gm0 = m0 + wm * 64 + mf * 16 + lq * 4;
    f32x4 rd;
    if constexpr (MODE == 1) {
      if constexpr (GATHER) {
        #pragma unroll
        for (int r = 0; r < 4; ++r)
          rd[r] = rdenom[(size_t)bat * NP + rowmap[gm0 + r]];
      } else {
        rd = *(const f32x4*)(rdenom + gm0);
      }
    }
    int rsm[4];
    if constexpr (GATHER && MODE == 0) {
      #pragma unroll
      for (int r = 0; r < 4; ++r) rsm[r] = rowmap[gm0 + r];
    }
    #pragma unroll
    for (int nf = 0; nf < 4; ++nf) {
      const int gn = n0 + wn * 64 + nf * 16 + lr;
      float vf[4];
      if constexpr (MODE == 0) {
        float xf[4];
        if constexpr (GATHER) {
          #pragma unroll
          for (int r = 0; r < 4; ++r)
            xf[r] = b2f(Xt[((size_t)bat * NP + rsm[r]) * 512 + gn]);
        } else {
          uchar4 xv = *(const uchar4*)(Bb + (size_t)gn * NP + gm0);
          xf[0] = f82f(xv.x); xf[1] = f82f(xv.y);
          xf[2] = f82f(xv.z); xf[3] = f82f(xv.w);
        }
        #pragma unroll
        for (int r = 0; r < 4; ++r) vf[r] = acc[mf][nf][r] * ascale + xf[r];
      } else if constexpr (MODE == 1) {
        const float bn = 2.f * bias[gn];
        #pragma unroll
        for (int r = 0; r < 4; ++r)
          vf[r] = fmaxf((acc[mf][nf][r] + bn) * rd[r], 0.f);
      } else {
        const float bn = bias[gn];
        #pragma unroll
        for (int r = 0; r < 4; ++r) vf[r] = acc[mf][nf][r] + bn;
      }
      #pragma unroll
      for (int r = 0; r < 4; ++r)
        out[outBase + (size_t)(gm0 + r) * 512 + gn] = f2b(vf[r]);
      if constexpr (WRITE_T) {
        const int bb = gm0 / NP;               // quad never straddles batch
        const int ml = gm0 - bb * NP;
        uchar4 tv;
        tv.x = f2f8(vf[0] * GSCALE); tv.y = f2f8(vf[1] * GSCALE);
        tv.z = f2f8(vf[2] * GSCALE); tv.w = f2f8(vf[3] * GSCALE);
        *(uchar4*)(outT + ((size_t)bb * 512 + gn) * NP + ml) = tv;
      }
    }
  }
}

// ----------------------------------------------------------- fused heads ---
// blocks [0,96): ner (4 rows/block, one per wave); blocks [96,608): pairs.
__global__ __launch_bounds__(256) void heads_kernel(
    const float* __restrict__ ner, const u16* __restrict__ logits_g,
    const float* __restrict__ nw, const float* __restrict__ nb,
    const float* __restrict__ refeat, const float* __restrict__ rw,
    const float* __restrict__ rb, const int* __restrict__ pslot,
    float* __restrict__ outp) {
  __shared__ float avg[D_];
  if (blockIdx.x < 96) {
    const int r = blockIdx.x * 4 + (threadIdx.x >> 6);   // 0..383
    const int b = r / SENT, tp = r % SENT;
    const int lane = threadIdx.x & 63;
    const float* nrow = ner      + ((size_t)b * SENT  + tp) * D_;
    const u16*   lrow = logits_g + ((size_t)b * SLOTB + tp) * D_;
    float rv[16];
    #pragma unroll
    for (int i = 0; i < 8; ++i) rv[i]     = nrow[lane + i * 64];
    #pragma unroll
    for (int i = 0; i < 8; ++i) rv[8 + i] = b2f(lrow[lane + i * 64]);
    for (int j = 0; j < NERL; ++j) {
      float s = 0.f;
      #pragma unroll
      for (int i = 0; i < 16; ++i)
        s = fmaf(rv[i], nw[(size_t)(lane + i * 64) * NERL + j], s);
      for (int o = 32; o > 0; o >>= 1) s += __shfl_down(s, o);
      if (lane == 0) outp[r * NERL + j] = s + nb[j];
    }
  } else {
    const int p = blockIdx.x - 96;
    const u16* r0 = logits_g + (size_t)pslot[p] * D_;   // 4 consecutive slots
    for (int dd = threadIdx.x; dd < D_; dd += 256)
      avg[dd] = 0.25f * (b2f(r0[dd]) + b2f(r0[D_ + dd]) +
                         b2f(r0[2 * D_ + dd]) + b2f(r0[3 * D_ + dd]));
    __syncthreads();
    const int wave = threadIdx.x >> 6, lane = threadIdx.x & 63;
    const float* rf = refeat + (size_t)p * D_;
    float* out = outp + B_ * SENT * NERL;
    for (int jj = 0; jj < 8; ++jj) {
      int j = wave * 8 + jj;
      float s = 0.f;
      #pragma unroll
      for (int i = 0; i < 8; ++i) {
        int k = lane + i * 64;
        s = fmaf(rf[k],  rw[(size_t)k * REL + j], s);
        s = fmaf(avg[k], rw[(size_t)(k + D_) * REL + j], s);
      }
      for (int o = 32; o > 0; o >>= 1) s += __shfl_down(s, o);
      if (lane == 0) out[p * REL + j] = s + rb[j];
    }
  }
}

// --------------------------------------------------------------- launch ----
extern "C" void kernel_launch(void* const* d_in, const int* in_sizes, int n_in,
                              void* d_out, int out_size, void* d_ws, size_t ws_size,
                              hipStream_t stream) {
  const float* inputs = (const float*)d_in[0];
  const float* ner    = (const float*)d_in[1];
  const float* refeat = (const float*)d_in[2];
  const float* adj    = (const float*)d_in[3];
  const float* W0w    = (const float*)d_in[4];
  const float* W0b    = (const float*)d_in[5];
  const float* W1w    = (const float*)d_in[6];
  const float* W1b    = (const float*)d_in[7];
  const float* outw   = (const float*)d_in[8];
  const float* outb   = (const float*)d_in[9];
  const float* nerw   = (const float*)d_in[10];
  const float* nerb   = (const float*)d_in[11];
  const float* rew    = (const float*)d_in[12];
  const float* reb    = (const float*)d_in[13];
  const int*   ps     = (const int*)d_in[14];
  const int*   hs     = (const int*)d_in[15];
  const int*   ts     = (const int*)d_in[16];
  (void)in_sizes; (void)n_in; (void)out_size; (void)ws_size;
  float* outp = (float*)d_out;

  char* ws = (char*)d_ws;
  size_t off = 0;
  u8* adj8 = (u8*)(ws + off); off += (size_t)B_ * NP * NP;        // 44.3 MB
  float* rdenom = (float*)(ws + off); off += (size_t)MTOT * 4;
  u16* zp  = (u16*)(ws + off); off += 1024;
  u16* w0t = (u16*)(ws + off); off += 512 * 512 * 2;
  u16* w1t = (u16*)(ws + off); off += 512 * 512 * 2;
  u16* owt = (u16*)(ws + off); off += 512 * 1024 * 2;
  u8*  xt8 = (u8*)(ws + off); off += (size_t)B_ * 512 * NP;       // x^T8 / g0^T8
  u16* S   = (u16*)(ws + off); off += (size_t)MTOT * 512 * 2;
  u16* g0  = (u16*)(ws + off); off += (size_t)MTOT * 512 * 2;
  int* rowmap = (int*)(ws + off); off += (size_t)MG * 4;
  int* pslot  = (int*)(ws + off); off += (size_t)PAIRS * 4;
  u16* S_g      = (u16*)(ws + off); off += (size_t)MG * 512 * 2;
  u16* g1_g     = (u16*)(ws + off); off += (size_t)MG * 512 * 2;
  u16* logits_g = (u16*)(ws + off); off += (size_t)MG * 512 * 2;

  // one fat prep dispatch: adj8+rdenom, zp, rowmap/pslot, all 4 transposes
  const int FATG = MTOT + 2 + 2368 + 64 + 64 + 128;   // 21442
  fat_prep<<<FATG, 256, 0, stream>>>(adj, inputs, W0w, W1w, outw, ps, hs, ts,
                                     adj8, rdenom, xt8, w0t, w1t, owt,
                                     rowmap, pslot, zp);

  // Layer 1: S = adj@x + x (fp8); g0 = relu((S@W0+2b)/denom) (+ g0^T fp8*32)
  gemm8<0,0,0><<<608, 256, 0, stream>>>(adj8, nullptr, xt8, nullptr,
                                        nullptr, nullptr, nullptr, zp, S,
                                        nullptr, 1.0f);
  gemm8<1,1,0><<<588, 256, 0, stream>>>(S, nullptr, w0t, nullptr,
                                        W0b, rdenom, nullptr, zp, g0,
                                        xt8, 1.0f);
  // Layer 2 (gathered, M = 5120 slots)
  gemm8<0,0,1><<<160, 256, 0, stream>>>(adj8, nullptr, xt8, g0,
                                        nullptr, nullptr, rowmap, zp, S_g,
                                        nullptr, 1.0f / GSCALE);
  gemm8<1,0,1><<<160, 256, 0, stream>>>(S_g, nullptr, w1t, nullptr,
                                        W1b, rdenom, rowmap, zp, g1_g,
                                        nullptr, 1.0f);
  gemm8<2,0,1><<<160, 256, 0, stream>>>(g0, g1_g, owt, nullptr,
                                        outb, nullptr, rowmap, zp, logits_g,
                                        nullptr, 1.0f);

  heads_kernel<<<608, 256, 0, stream>>>(ner, logits_g, nerw, nerb,
                                        refeat, rew, reb, pslot, outp);
}

// Round 15
// 284.527 us; speedup vs baseline: 1.3784x; 1.1477x over previous
//
#include <hip/hip_runtime.h>
#include <hip/hip_bf16.h>

#define B_    8
#define NP    2352
#define D_    512
#define SENT  48
#define PAIRS 512
#define NERL  16
#define REL   32
#define MTOT  (B_*NP)   // 18816
#define SLOTB 640       // slots per batch (48 ner + up to 148 pairs * 4)
#define MG    (B_*SLOTB) // 5120 gathered slots = 40 tiles of 128
#define GSCALE 32.0f    // g0 -> fp8 pre-scale (avoids e4m3 denormal region)

typedef unsigned short u16;
typedef unsigned char  u8;
typedef __bf16 bf16x8 __attribute__((ext_vector_type(8)));
typedef float  f32x4  __attribute__((ext_vector_type(4)));

__device__ __forceinline__ u16 f2b(float f) {
  union { float f; unsigned u; } c; c.f = f;
  unsigned u = c.u;
  u += 0x7fffu + ((u >> 16) & 1u);           // round-to-nearest-even
  return (u16)(u >> 16);
}
__device__ __forceinline__ float b2f(u16 h) {
  union { unsigned u; float f; } c; c.u = ((unsigned)h) << 16;
  return c.f;
}
// ---- e4m3fn encode (soft fallback) ----
__device__ __forceinline__ u8 f2f8(float f) {
  unsigned u = __float_as_uint(f);
  u8 s = (u >> 24) & 0x80;
  float a = fabsf(f);
  if (a < 0.0009765625f) return s;            // < 2^-10 -> 0
  if (a >= 448.f) return s | 0x7E;            // clamp to max finite 448
  int e = ((u >> 23) & 0xFF) - 127;
  if (e < -6) {                               // denormal: m * 2^-9
    int q = (int)(a * 512.f + 0.5f);
    if (q >= 8) return s | 0x08;
    return s | (u8)q;
  }
  float sc = __uint_as_float((unsigned)((127 - e) << 23));   // 2^-e
  int q = (int)(a * sc * 8.f + 0.5f);          // 8..16
  if (q >= 16) { q = 8; ++e; if (e > 8) return s | 0x7E; }
  return s | (u8)(((e + 7) << 3) | (q - 8));
}
// ---- HW packed f32x4 -> fp8x4 (gfx950 HW fp8 = OCP e4m3fn, same as MFMA) --
#if defined(__has_builtin)
#if __has_builtin(__builtin_amdgcn_cvt_pk_fp8_f32)
#define HAVE_CVT_FP8 1
#endif
#endif
__device__ __forceinline__ unsigned f2f8x4(float a, float b, float c, float d) {
#ifdef HAVE_CVT_FP8
  unsigned w = 0;
  w = __builtin_amdgcn_cvt_pk_fp8_f32(a, b, w, false);   // bytes 0,1
  w = __builtin_amdgcn_cvt_pk_fp8_f32(c, d, w, true);    // bytes 2,3
  return w;
#else
  return (unsigned)f2f8(a) | ((unsigned)f2f8(b) << 8) |
         ((unsigned)f2f8(c) << 16) | ((unsigned)f2f8(d) << 24);
#endif
}
__device__ __forceinline__ float f82f(u8 v) {
  unsigned s = ((unsigned)(v & 0x80u)) << 24;
  unsigned e = (v >> 3) & 0xF, m = v & 7;
  if (e == 0) {
    if (m == 0) return __uint_as_float(s);
    float f = (float)m * 0.001953125f;         // m * 2^-9
    return __uint_as_float(s | __float_as_uint(f));
  }
  return __uint_as_float(s | ((e + 120u) << 23) | (m << 20));
}
__device__ __forceinline__ void gload16(const void* g, void* lds) {
  __builtin_amdgcn_global_load_lds(
      (const __attribute__((address_space(1))) unsigned*)g,
      (__attribute__((address_space(3))) unsigned*)lds, 16, 0, 0);
}

// ----------------------------------------------------- transpose-convert ---
// in [R][C] f32 -> out [C][R] (bf16 or fp8), one 64x64 tile.
template<int OUT8>
__device__ __forceinline__ void tcvt_body(const float* __restrict__ in_,
                                          void* __restrict__ out,
                                          int R, int C, int b, int r0, int c0,
                                          size_t inb, size_t outb,
                                          u16 tile[64][65]) {
  const int t  = threadIdx.x;
  const int tr = t >> 4, tc = (t & 15) * 4;
  #pragma unroll
  for (int i = 0; i < 4; ++i) {
    int rl = i * 16 + tr;
    int r  = r0 + rl;
    if (r < R) {
      const float* in = in_ + (size_t)b * inb + (size_t)r * C + c0 + tc;
      float4 v = *(const float4*)in;
      tile[rl][tc + 0] = f2b(v.x); tile[rl][tc + 1] = f2b(v.y);
      tile[rl][tc + 2] = f2b(v.z); tile[rl][tc + 3] = f2b(v.w);
    }
  }
  __syncthreads();
  const int c  = t >> 2;
  const int rb = (t & 3) * 16;
  #pragma unroll
  for (int i = 0; i < 4; ++i) {
    int rl = rb + i * 4;
    int r  = r0 + rl;
    if (OUT8) {
      u8* orow = (u8*)out + (size_t)b * outb + (size_t)(c0 + c) * R + r0;
      if (r + 3 < R) {
        *(unsigned*)(orow + rl) =
            f2f8x4(b2f(tile[rl + 0][c]), b2f(tile[rl + 1][c]),
                   b2f(tile[rl + 2][c]), b2f(tile[rl + 3][c]));
      } else {
        for (int j = 0; j < 4; ++j)
          if (r + j < R) orow[rl + j] = f2f8(b2f(tile[rl + j][c]));
      }
    } else {
      u16* orow = (u16*)out + (size_t)b * outb + (size_t)(c0 + c) * R + r0;
      if (r + 3 < R) {
        ushort4 v;
        v.x = tile[rl + 0][c]; v.y = tile[rl + 1][c];
        v.z = tile[rl + 2][c]; v.w = tile[rl + 3][c];
        *(ushort4*)(orow + rl) = v;
      } else {
        for (int j = 0; j < 4; ++j)
          if (r + j < R) orow[rl + j] = tile[rl + j][c];
      }
    }
  }
}

// -------------------------------------------------------------- fat prep ---
// One dispatch covering all independent preprocessing:
//  blocks [0, MTOT)        : adj f32 -> fp8 + rowsum -> rdenom (one row each)
//  block  MTOT             : zero the zero-page
//  block  MTOT+1           : rowmap/pslot build (deterministic ranks)
//  blocks [MTOT+2, +2368)  : x^T fp8 tcvt (37x8 tiles x 8 batches)
//  next 64 / 64 / 128      : W0^T, W1^T, outw^T bf16 tcvt
__global__ __launch_bounds__(256) void fat_prep(
    const float* __restrict__ adj, const float* __restrict__ inputs,
    const float* __restrict__ W0w, const float* __restrict__ W1w,
    const float* __restrict__ outw,
    const int* __restrict__ ps, const int* __restrict__ hs,
    const int* __restrict__ ts,
    u8* __restrict__ adj8, float* __restrict__ rdenom,
    u8* __restrict__ xt8, u16* __restrict__ w0t, u16* __restrict__ w1t,
    u16* __restrict__ owt, int* __restrict__ rowmap, int* __restrict__ pslot,
    u16* __restrict__ zp) {
  __shared__ u16 tile[64][65];
  __shared__ int sps[PAIRS];
  __shared__ float red[4];
  const int bx = blockIdx.x;
  const int t  = threadIdx.x;

  if (bx < MTOT) {                            // ---- prep_adj row
    const int row = bx;
    const float4* src = (const float4*)(adj + (size_t)row * NP);
    u8* dst = adj8 + (size_t)row * NP;
    float s = 0.f;
    for (int i = t; i < NP / 4; i += 256) {
      float4 v = src[i];
      s += (v.x + v.y) + (v.z + v.w);
      *(unsigned*)(dst + i * 4) = f2f8x4(v.x, v.y, v.z, v.w);
    }
    #pragma unroll
    for (int o = 32; o > 0; o >>= 1) s += __shfl_down(s, o, 64);
    int w = t >> 6, l = t & 63;
    if (l == 0) red[w] = s;
    __syncthreads();
    if (t == 0)
      rdenom[row] = 1.f / (red[0] + red[1] + red[2] + red[3] + 1.f);
  } else if (bx == MTOT) {                    // ---- zero page
    zp[t] = 0; zp[256 + t] = 0;
  } else if (bx == MTOT + 1) {                // ---- rowmap / pslot
    sps[t] = ps[t]; sps[256 + t] = ps[256 + t];
    for (int i = t; i < MG; i += 256) rowmap[i] = 0;
    __syncthreads();
    for (int u = t; u < B_ * SENT; u += 256)
      rowmap[(u / SENT) * SLOTB + (u % SENT)] = u % SENT;
    for (int p = t; p < PAIRS; p += 256) {
      const int b = sps[p];
      int rank = 0;
      for (int q = 0; q < p; ++q) rank += (sps[q] == b) ? 1 : 0;
      const int h = hs[p], tt = ts[p];
      const int s0 = b * SLOTB + SENT + 4 * rank;
      rowmap[s0 + 0] = (h + 1) * SENT + tt;
      rowmap[s0 + 1] = (h + 1) * SENT + tt + 1;
      rowmap[s0 + 2] = (h + 2) * SENT + tt;
      rowmap[s0 + 3] = (h + 2) * SENT + tt + 1;
      pslot[p] = s0;
    }
  } else {                                    // ---- tcvt region
    int r = bx - (MTOT + 2);
    if (r < 2368) {                           // x^T fp8: 296 tiles x 8 batches
      const int b = r / 296, rem = r % 296;
      const int rx = rem % 37, ry = rem / 37;
      tcvt_body<1>(inputs, xt8, NP, D_, b, rx * 64, ry * 64,
                   (size_t)NP * D_, (size_t)D_ * NP, tile);
    } else if ((r -= 2368) < 64) {            // W0^T bf16
      tcvt_body<0>(W0w, w0t, 512, 512, 0, (r % 8) * 64, (r / 8) * 64,
                   0, 0, tile);
    } else if ((r -= 64) < 64) {              // W1^T bf16
      tcvt_body<0>(W1w, w1t, 512, 512, 0, (r % 8) * 64, (r / 8) * 64,
                   0, 0, tile);
    } else {                                  // outw^T bf16 (1024x512)
      r -= 64;
      tcvt_body<0>(outw, owt, 1024, 512, 0, (r % 16) * 64, (r / 16) * 64,
                   0, 0, tile);
    }
  }
}

// ------------------------------------------- 4-wave 128x128 GEMM core ------
// R13 structure unchanged: BM=BN=128, BK=64, dbuf-2, T3-min schedule,
// both-sides 16B-chunk swizzle, zero-page K-tail, 2+ blocks/CU.
// MODE 0 fp8 e4m3 (A=adj8, B=x^T8/g0^T8*32); MODE 1/2 bf16.
// MODE 1 GATHER gathers rdenom directly via rowmap.
template<int MODE, int WRITE_T, int GATHER>
__global__ __launch_bounds__(256, 2) void gemm8(
    const void* __restrict__ A, const void* __restrict__ A2,
    const void* __restrict__ Bm, const u16* __restrict__ Xt,
    const float* __restrict__ bias, const float* __restrict__ rdenom,
    const int* __restrict__ rowmap,
    const u16* __restrict__ zp, u16* __restrict__ out, u8* __restrict__ outT,
    float ascale)
{
  constexpr bool F8   = (MODE == 0);
  constexpr int KACT   = (MODE == 0) ? NP : (MODE == 1 ? 512 : 1024);
  constexpr int KTILES = (KACT + 63) / 64;     // 37 / 8 / 16
  constexpr int EPC    = F8 ? 16 : 8;          // elements per 16B chunk
  constexpr int CPT    = F8 ? 4 : 8;           // chunks per row per K-tile
  constexpr int NJ     = F8 ? 2 : 4;           // stage issues per thread
  constexpr int ABYTES = F8 ? 8192 : 16384;    // bytes per dbuf per operand

  int m0, n0, bat = 0;
  const u8* Ab = (const u8*)A;
  const u8* Bb = (const u8*)Bm;
  size_t outBase = 0;
  if constexpr (GATHER) {
    // grid 160 = 8 XCDs x 20; 40 m-tiles (5/batch) x 4 n-tiles
    const int bx  = blockIdx.x;
    const int rid = (bx & 7) * 20 + (bx >> 3);
    const int mt  = rid >> 2;                 // 0..39
    n0 = (rid & 3) << 7;
    m0 = mt * 128;                            // slot-space
    bat = mt / 5;
    if constexpr (MODE == 0) {
      Ab = (const u8*)A  + (size_t)bat * NP * NP;       // adj8
      Bb = (const u8*)Bm + (size_t)bat * 512 * NP;      // g0t8
    }
  } else if constexpr (MODE == 0) {
    // grid 608 = 8 XCD chunks x 76 (one batch per chunk); 19 m x 4 n
    const int bx  = blockIdx.x;
    bat = bx & 7;
    const int loc = bx >> 3;                  // 0..75
    const int mt  = loc >> 2;                 // 0..18
    n0 = (loc & 3) << 7;
    m0 = (mt < 18) ? mt * 128 : NP - 128;     // overlap last tile
    Ab = (const u8*)A  + (size_t)bat * NP * NP;
    Bb = (const u8*)Bm + (size_t)bat * 512 * NP;
    outBase = (size_t)bat * NP * 512;
  } else {
    // grid 588 = 147 m x 4 n; bijective XCD chunking (q=73, r=4)
    const int bx  = blockIdx.x;
    const int xcd = bx & 7, pos = bx >> 3;
    const int rid = (xcd < 4) ? xcd * 74 + pos : 296 + (xcd - 4) * 73 + pos;
    const int mt  = rid >> 2;                 // 0..146
    n0 = (rid & 3) << 7;
    m0 = mt * 128;                            // exact (147*128 = 18816)
  }

  __shared__ __align__(16) u8 As[2 * ABYTES];
  __shared__ __align__(16) u8 Bs[2 * ABYTES];

  const int tid = threadIdx.x;
  const int l  = tid & 63;
  const int w  = tid >> 6;
  const int wm = w >> 1, wn = w & 1;
  const int lr = l & 15, lq = l >> 4;

  f32x4 acc[4][4];
  #pragma unroll
  for (int i = 0; i < 4; ++i)
    #pragma unroll
    for (int j = 0; j < 4; ++j)
      acc[i][j] = (f32x4){0.f, 0.f, 0.f, 0.f};

  int rsrc[2];
  #pragma unroll
  for (int j = 0; j < 2; ++j) {
    const int row = j * 64 + (tid >> 2);
    if constexpr (GATHER && MODE != 1) rsrc[j] = rowmap[m0 + row];
    else                               rsrc[j] = m0 + row;
  }

  auto STAGE = [&](int isA, int d, int kt) {
    #pragma unroll
    for (int j = 0; j < NJ; ++j) {
      const int cl   = j * 256 + tid;
      const int row  = (cl >> 2) & 127;
      const int slot = cl & 3;
      const int s    = F8 ? 0 : (cl >> 9);
      const int gch  = kt * CPT + s * 4 + (slot ^ ((row >> 1) & 3));
      const u8* src;
      if (isA) {
        if constexpr (MODE == 0) {
          src = Ab + (size_t)rsrc[j & 1] * NP + (size_t)gch * 16;
        } else if constexpr (MODE == 1) {
          src = (const u8*)A + ((size_t)(m0 + row) * 512 + (size_t)gch * 8) * 2;
        } else {   // MODE 2: concat(g0, g1) over k
          int rg = (GATHER ? rsrc[j & 1] : (m0 + row));
          src = (gch < 64)
              ? (const u8*)A  + (((size_t)(GATHER ? bat * NP : 0) + rg) * 512
                                 + (size_t)gch * 8) * 2
              : (const u8*)A2 + ((size_t)(m0 + row) * 512
                                 + (size_t)(gch - 64) * 8) * 2;
        }
        if (gch * EPC + EPC > KACT) src = (const u8*)zp;
        gload16(src, As + d * ABYTES + cl * 16);
      } else {
        if constexpr (F8)
          src = Bb + (size_t)(n0 + row) * NP + (size_t)gch * 16;
        else
          src = (const u8*)Bm + ((size_t)(n0 + row) * KACT + (size_t)gch * 8) * 2;
        if (gch * EPC + EPC > KACT) src = (const u8*)zp;
        gload16(src, Bs + d * ABYTES + cl * 16);
      }
    }
  };

  // prologue: tile 0 into buf 0
  STAGE(1, 0, 0);
  STAGE(0, 0, 0);
  asm volatile("s_waitcnt vmcnt(0)" ::: "memory");
  __builtin_amdgcn_s_barrier();

  int d = 0;
  for (int kt = 0; kt < KTILES; ++kt) {
    if (kt + 1 < KTILES) {
      STAGE(1, d ^ 1, kt + 1);
      STAGE(0, d ^ 1, kt + 1);
    }
    const u8* Ad = As + d * ABYTES;
    const u8* Bd = Bs + d * ABYTES;
    if constexpr (F8) {
      long a0[4], b0[4], a1[4], b1[4];
      #pragma unroll
      for (int f = 0; f < 4; ++f) {
        const int ra = wm * 64 + f * 16 + lr;
        const int rb = wn * 64 + f * 16 + lr;
        const int swa = (ra >> 1) & 3, swb = (rb >> 1) & 3;
        const int co = (lq >> 1), bo = (lq & 1) << 3;
        a0[f] = *(const long*)(Ad + ra * 64 + (((0 + co) ^ swa) << 4) + bo);
        b0[f] = *(const long*)(Bd + rb * 64 + (((0 + co) ^ swb) << 4) + bo);
        a1[f] = *(const long*)(Ad + ra * 64 + (((2 + co) ^ swa) << 4) + bo);
        b1[f] = *(const long*)(Bd + rb * 64 + (((2 + co) ^ swb) << 4) + bo);
      }
      asm volatile("s_waitcnt lgkmcnt(0)" ::: "memory");
      __builtin_amdgcn_sched_barrier(0);
      __builtin_amdgcn_s_setprio(1);
      #pragma unroll
      for (int mf = 0; mf < 4; ++mf)
        #pragma unroll
        for (int nf = 0; nf < 4; ++nf)
          acc[mf][nf] = __builtin_amdgcn_mfma_f32_16x16x32_fp8_fp8(
              a0[mf], b0[nf], acc[mf][nf], 0, 0, 0);
      #pragma unroll
      for (int mf = 0; mf < 4; ++mf)
        #pragma unroll
        for (int nf = 0; nf < 4; ++nf)
          acc[mf][nf] = __builtin_amdgcn_mfma_f32_16x16x32_fp8_fp8(
              a1[mf], b1[nf], acc[mf][nf], 0, 0, 0);
      __builtin_amdgcn_s_setprio(0);
      __builtin_amdgcn_sched_barrier(0);
    } else {
      bf16x8 a0[4], b0[4], a1[4], b1[4];
      #pragma unroll
      for (int f = 0; f < 4; ++f) {
        const int ra = wm * 64 + f * 16 + lr;
        const int rb = wn * 64 + f * 16 + lr;
        const int sa = (lq ^ ((ra >> 1) & 3)) << 4;
        const int sb = (lq ^ ((rb >> 1) & 3)) << 4;
        a0[f] = *(const bf16x8*)(Ad + ra * 64 + sa);
        b0[f] = *(const bf16x8*)(Bd + rb * 64 + sb);
        a1[f] = *(const bf16x8*)(Ad + 8192 + ra * 64 + sa);
        b1[f] = *(const bf16x8*)(Bd + 8192 + rb * 64 + sb);
      }
      asm volatile("s_waitcnt lgkmcnt(0)" ::: "memory");
      __builtin_amdgcn_sched_barrier(0);
      __builtin_amdgcn_s_setprio(1);
      #pragma unroll
      for (int mf = 0; mf < 4; ++mf)
        #pragma unroll
        for (int nf = 0; nf < 4; ++nf)
          acc[mf][nf] = __builtin_amdgcn_mfma_f32_16x16x32_bf16(
              a0[mf], b0[nf], acc[mf][nf], 0, 0, 0);
      #pragma unroll
      for (int mf = 0; mf < 4; ++mf)
        #pragma unroll
        for (int nf = 0; nf < 4; ++nf)
          acc[mf][nf] = __builtin_amdgcn_mfma_f32_16x16x32_bf16(
              a1[mf], b1[nf], acc[mf][nf], 0, 0, 0);
      __builtin_amdgcn_s_setprio(0);
      __builtin_amdgcn_sched_barrier(0);
    }
    asm volatile("s_waitcnt vmcnt(0)" ::: "memory");  // next tile landed
    __builtin_amdgcn_s_barrier();
    d ^= 1;
  }

  // --------------------------------------------------------- epilogue ----
  #pragma unroll
  for (int mf = 0; mf < 4; ++mf) {
    const int gm0 = m0 + wm * 64 + mf * 16 + lq * 4;
    f32x4 rd;
    if constexpr (MODE == 1) {
      if constexpr (GATHER) {
        #pragma unroll
        for (int r = 0; r < 4; ++r)
          rd[r] = rdenom[(size_t)bat * NP + rowmap[gm0 + r]];
      } else {
        rd = *(const f32x4*)(rdenom + gm0);
      }
    }
    int rsm[4];
    if constexpr (GATHER && MODE == 0) {
      #pragma unroll
      for (int r = 0; r < 4; ++r) rsm[r] = rowmap[gm0 + r];
    }
    #pragma unroll
    for (int nf = 0; nf < 4; ++nf) {
      const int gn = n0 + wn * 64 + nf * 16 + lr;
      float vf[4];
      if constexpr (MODE == 0) {
        float xf[4];
        if constexpr (GATHER) {
          #pragma unroll
          for (int r = 0; r < 4; ++r)
            xf[r] = b2f(Xt[((size_t)bat * NP + rsm[r]) * 512 + gn]);
        } else {
          uchar4 xv = *(const uchar4*)(Bb + (size_t)gn * NP + gm0);
          xf[0] = f82f(xv.x); xf[1] = f82f(xv.y);
          xf[2] = f82f(xv.z); xf[3] = f82f(xv.w);
        }
        #pragma unroll
        for (int r = 0; r < 4; ++r) vf[r] = acc[mf][nf][r] * ascale + xf[r];
      } else if constexpr (MODE == 1) {
        const float bn = 2.f * bias[gn];
        #pragma unroll
        for (int r = 0; r < 4; ++r)
          vf[r] = fmaxf((acc[mf][nf][r] + bn) * rd[r], 0.f);
      } else {
        const float bn = bias[gn];
        #pragma unroll
        for (int r = 0; r < 4; ++r) vf[r] = acc[mf][nf][r] + bn;
      }
      #pragma unroll
      for (int r = 0; r < 4; ++r)
        out[outBase + (size_t)(gm0 + r) * 512 + gn] = f2b(vf[r]);
      if constexpr (WRITE_T) {
        const int bb = gm0 / NP;               // quad never straddles batch
        const int ml = gm0 - bb * NP;
        *(unsigned*)(outT + ((size_t)bb * 512 + gn) * NP + ml) =
            f2f8x4(vf[0] * GSCALE, vf[1] * GSCALE,
                   vf[2] * GSCALE, vf[3] * GSCALE);
      }
    }
  }
}

// ----------------------------------------------------------- fused heads ---
// blocks [0,96): ner (4 rows/block, one per wave); blocks [96,608): pairs.
__global__ __launch_bounds__(256) void heads_kernel(
    const float* __restrict__ ner, const u16* __restrict__ logits_g,
    const float* __restrict__ nw, const float* __restrict__ nb,
    const float* __restrict__ refeat, const float* __restrict__ rw,
    const float* __restrict__ rb, const int* __restrict__ pslot,
    float* __restrict__ outp) {
  __shared__ float avg[D_];
  if (blockIdx.x < 96) {
    const int r = blockIdx.x * 4 + (threadIdx.x >> 6);   // 0..383
    const int b = r / SENT, tp = r % SENT;
    const int lane = threadIdx.x & 63;
    const float* nrow = ner      + ((size_t)b * SENT  + tp) * D_;
    const u16*   lrow = logits_g + ((size_t)b * SLOTB + tp) * D_;
    float rv[16];
    #pragma unroll
    for (int i = 0; i < 8; ++i) rv[i]     = nrow[lane + i * 64];
    #pragma unroll
    for (int i = 0; i < 8; ++i) rv[8 + i] = b2f(lrow[lane + i * 64]);
    for (int j = 0; j < NERL; ++j) {
      float s = 0.f;
      #pragma unroll
      for (int i = 0; i < 16; ++i)
        s = fmaf(rv[i], nw[(size_t)(lane + i * 64) * NERL + j], s);
      for (int o = 32; o > 0; o >>= 1) s += __shfl_down(s, o);
      if (lane == 0) outp[r * NERL + j] = s + nb[j];
    }
  } else {
    const int p = blockIdx.x - 96;
    const u16* r0 = logits_g + (size_t)pslot[p] * D_;   // 4 consecutive slots
    for (int dd = threadIdx.x; dd < D_; dd += 256)
      avg[dd] = 0.25f * (b2f(r0[dd]) + b2f(r0[D_ + dd]) +
                         b2f(r0[2 * D_ + dd]) + b2f(r0[3 * D_ + dd]));
    __syncthreads();
    const int wave = threadIdx.x >> 6, lane = threadIdx.x & 63;
    const float* rf = refeat + (size_t)p * D_;
    float* out = outp + B_ * SENT * NERL;
    for (int jj = 0; jj < 8; ++jj) {
      int j = wave * 8 + jj;
      float s = 0.f;
      #pragma unroll
      for (int i = 0; i < 8; ++i) {
        int k = lane + i * 64;
        s = fmaf(rf[k],  rw[(size_t)k * REL + j], s);
        s = fmaf(avg[k], rw[(size_t)(k + D_) * REL + j], s);
      }
      for (int o = 32; o > 0; o >>= 1) s += __shfl_down(s, o);
      if (lane == 0) out[p * REL + j] = s + rb[j];
    }
  }
}

// --------------------------------------------------------------- launch ----
extern "C" void kernel_launch(void* const* d_in, const int* in_sizes, int n_in,
                              void* d_out, int out_size, void* d_ws, size_t ws_size,
                              hipStream_t stream) {
  const float* inputs = (const float*)d_in[0];
  const float* ner    = (const float*)d_in[1];
  const float* refeat = (const float*)d_in[2];
  const float* adj    = (const float*)d_in[3];
  const float* W0w    = (const float*)d_in[4];
  const float* W0b    = (const float*)d_in[5];
  const float* W1w    = (const float*)d_in[6];
  const float* W1b    = (const float*)d_in[7];
  const float* outw   = (const float*)d_in[8];
  const float* outb   = (const float*)d_in[9];
  const float* nerw   = (const float*)d_in[10];
  const float* nerb   = (const float*)d_in[11];
  const float* rew    = (const float*)d_in[12];
  const float* reb    = (const float*)d_in[13];
  const int*   ps     = (const int*)d_in[14];
  const int*   hs     = (const int*)d_in[15];
  const int*   ts     = (const int*)d_in[16];
  (void)in_sizes; (void)n_in; (void)out_size; (void)ws_size;
  float* outp = (float*)d_out;

  char* ws = (char*)d_ws;
  size_t off = 0;
  u8* adj8 = (u8*)(ws + off); off += (size_t)B_ * NP * NP;        // 44.3 MB
  float* rdenom = (float*)(ws + off); off += (size_t)MTOT * 4;
  u16* zp  = (u16*)(ws + off); off += 1024;
  u16* w0t = (u16*)(ws + off); off += 512 * 512 * 2;
  u16* w1t = (u16*)(ws + off); off += 512 * 512 * 2;
  u16* owt = (u16*)(ws + off); off += 512 * 1024 * 2;
  u8*  xt8 = (u8*)(ws + off); off += (size_t)B_ * 512 * NP;       // x^T8 / g0^T8
  u16* S   = (u16*)(ws + off); off += (size_t)MTOT * 512 * 2;
  u16* g0  = (u16*)(ws + off); off += (size_t)MTOT * 512 * 2;
  int* rowmap = (int*)(ws + off); off += (size_t)MG * 4;
  int* pslot  = (int*)(ws + off); off += (size_t)PAIRS * 4;
  u16* S_g      = (u16*)(ws + off); off += (size_t)MG * 512 * 2;
  u16* g1_g     = (u16*)(ws + off); off += (size_t)MG * 512 * 2;
  u16* logits_g = (u16*)(ws + off); off += (size_t)MG * 512 * 2;

  // one fat prep dispatch: adj8+rdenom, zp, rowmap/pslot, all 4 transposes
  const int FATG = MTOT + 2 + 2368 + 64 + 64 + 128;   // 21442
  fat_prep<<<FATG, 256, 0, stream>>>(adj, inputs, W0w, W1w, outw, ps, hs, ts,
                                     adj8, rdenom, xt8, w0t, w1t, owt,
                                     rowmap, pslot, zp);

  // Layer 1: S = adj@x + x (fp8); g0 = relu((S@W0+2b)/denom) (+ g0^T fp8*32)
  gemm8<0,0,0><<<608, 256, 0, stream>>>(adj8, nullptr, xt8, nullptr,
                                        nullptr, nullptr, nullptr, zp, S,
                                        nullptr, 1.0f);
  gemm8<1,1,0><<<588, 256, 0, stream>>>(S, nullptr, w0t, nullptr,
                                        W0b, rdenom, nullptr, zp, g0,
                                        xt8, 1.0f);
  // Layer 2 (gathered, M = 5120 slots)
  gemm8<0,0,1><<<160, 256, 0, stream>>>(adj8, nullptr, xt8, g0,
                                        nullptr, nullptr, rowmap, zp, S_g,
                                        nullptr, 1.0f / GSCALE);
  gemm8<1,0,1><<<160, 256, 0, stream>>>(S_g, nullptr, w1t, nullptr,
                                        W1b, rdenom, rowmap, zp, g1_g,
                                        nullptr, 1.0f);
  gemm8<2,0,1><<<160, 256, 0, stream>>>(g0, g1_g, owt, nullptr,
                                        outb, nullptr, rowmap, zp, logits_g,
                                        nullptr, 1.0f);

  heads_kernel<<<608, 256, 0, stream>>>(ner, logits_g, nerw, nerb,
                                        refeat, rew, reb, pslot, outp);
}